// Round 10
// baseline (2617.474 us; speedup 1.0000x reference)
//
#include <hip/hip_runtime.h>
#include <hip/hip_cooperative_groups.h>
#include <cstdint>
#include <cstddef>

namespace cg = cooperative_groups;

#define TPB 256
#define NCU 256

typedef float f32x4 __attribute__((ext_vector_type(4)));
typedef float f32x2 __attribute__((ext_vector_type(2)));
typedef int   i32x4 __attribute__((ext_vector_type(4)));

static inline int cdiv(long long a, int b){ return (int)((a + (long long)b - 1) / b); }

// ---- concat level tables: N={16384,4096,1024,256,16384}, E={196608,49152,12288,3072,196608}
#define NTOT 38144
#define ETOT 457728
#define CTOT 610304
#define RPTOT 38149

// ---------------- small vector helpers ----------------

template<int W>
__device__ __forceinline__ void vload(const float* __restrict__ p, float* r){
  if constexpr (W == 8){ vload<4>(p, r); vload<4>(p+4, r+4); }
  else if constexpr (W == 4){ f32x4 v = *reinterpret_cast<const f32x4*>(p); r[0]=v.x;r[1]=v.y;r[2]=v.z;r[3]=v.w; }
  else { f32x2 v = *reinterpret_cast<const f32x2*>(p); r[0]=v.x;r[1]=v.y; }
}
template<int W>
__device__ __forceinline__ void vstore(float* __restrict__ p, const float* r){
  if constexpr (W == 8){ vstore<4>(p, r); vstore<4>(p+4, r+4); }
  else if constexpr (W == 4){ f32x4 v; v.x=r[0];v.y=r[1];v.z=r[2];v.w=r[3]; *reinterpret_cast<f32x4*>(p) = v; }
  else { f32x2 v; v.x=r[0];v.y=r[1]; *reinterpret_cast<f32x2*>(p) = v; }
}

template<int F>
__device__ __forceinline__ void loadrow(const float* __restrict__ p, float* r){
  #pragma unroll
  for (int q = 0; q < F/4; ++q) vload<4>(p + 4*q, r + 4*q);
}
template<int F>
__device__ __forceinline__ void storerow(float* __restrict__ p, const float* r){
  #pragma unroll
  for (int q = 0; q < F/4; ++q) vstore<4>(p + 4*q, r + 4*q);
}

// ---------------- CSR build (fused across 5 levels) ----------------

__device__ __forceinline__ bool lvl_edge(int t, const int* e0,const int* e1,const int* e2,const int* e3,const int* e4,
                                         const int*& ei, int& E, int& noff, int& rpoff, int& rel){
  if (t < 196608){ ei=e0; E=196608; noff=0;     rpoff=0;     rel=t;        return true; }
  if (t < 245760){ ei=e1; E=49152;  noff=16384; rpoff=16385; rel=t-196608; return true; }
  if (t < 258048){ ei=e2; E=12288;  noff=20480; rpoff=20482; rel=t-245760; return true; }
  if (t < 261120){ ei=e3; E=3072;   noff=21504; rpoff=21507; rel=t-258048; return true; }
  if (t < 457728){ ei=e4; E=196608; noff=21760; rpoff=21764; rel=t-261120; return true; }
  return false;
}

__global__ void k_degs_all(const int* e0,const int* e1,const int* e2,const int* e3,const int* e4,
                           int* __restrict__ rowdeg, int* __restrict__ dstdeg){
  int t = blockIdx.x*blockDim.x + threadIdx.x;
  const int* ei; int E, noff, rpoff, rel;
  if (!lvl_edge(t, e0,e1,e2,e3,e4, ei,E,noff,rpoff,rel)) return;
  atomicAdd(&rowdeg[noff + ei[rel]], 1);
  atomicAdd(&dstdeg[noff + ei[E + rel]], 1);
}

__global__ void k_dis_all(const int* __restrict__ rowdeg, float* __restrict__ dis){
  int t = blockIdx.x*blockDim.x + threadIdx.x;
  if (t >= NTOT) return;
  int d = rowdeg[t];
  dis[t] = d > 0 ? rsqrtf((float)d) : 0.f;
}

__global__ void k_scan5(const int* __restrict__ dstdeg, int* __restrict__ rp, int* __restrict__ cursor){
  const int NnA[5]  = {16384,4096,1024,256,16384};
  const int NOFF[5] = {0,16384,20480,21504,21760};
  const int COFF[5] = {0,262144,327680,344064,348160};
  __shared__ int part[257];
  int l = blockIdx.x;
  int N = NnA[l];
  const int* cnt = dstdeg + NOFF[l];
  int* rpl = rp + NOFF[l] + l;
  int* cul = cursor + NOFF[l] + l;
  int tid = threadIdx.x;
  int chunk = (N + 255) / 256;
  int lo = tid*chunk; if (lo > N) lo = N;
  int hi = lo + chunk; if (hi > N) hi = N;
  int s = 0;
  for (int i = lo; i < hi; ++i) s += (cnt[i] + 3) & ~3;
  part[tid+1] = s;
  if (tid == 0) part[0] = COFF[l];
  __syncthreads();
  if (tid == 0){ for (int i = 1; i <= 256; ++i) part[i] += part[i-1]; }
  __syncthreads();
  int run = part[tid];
  for (int i = lo; i < hi; ++i){ rpl[i] = run; cul[i] = run; run += (cnt[i] + 3) & ~3; }
  if (tid == 0) rpl[N] = part[256];
}

__global__ void k_fill_all(const int* e0,const int* e1,const int* e2,const int* e3,const int* e4,
                           const float* __restrict__ dis, int* __restrict__ cursor,
                           int* __restrict__ srcs, float* __restrict__ w){
  int t = blockIdx.x*blockDim.x + threadIdx.x;
  const int* ei; int E, noff, rpoff, rel;
  if (!lvl_edge(t, e0,e1,e2,e3,e4, ei,E,noff,rpoff,rel)) return;
  int src = ei[rel], dst = ei[E + rel];
  int pos = atomicAdd(&cursor[rpoff + dst], 1);
  srcs[pos] = src;
  w[pos] = dis[noff + src] * dis[noff + dst];
}

__global__ void k_pad_all(const int* __restrict__ dstdeg, const int* __restrict__ rp,
                          int* __restrict__ srcs, float* __restrict__ w){
  int t = blockIdx.x*blockDim.x + threadIdx.x;
  if (t >= NTOT) return;
  int rpoff, n;
  if      (t < 16384){ rpoff = 0;     n = t; }
  else if (t < 20480){ rpoff = 16385; n = t - 16384; }
  else if (t < 21504){ rpoff = 20482; n = t - 20480; }
  else if (t < 21760){ rpoff = 21507; n = t - 21504; }
  else               { rpoff = 21764; n = t - 21760; }
  int j0 = rp[rpoff + n];
  int j1 = rp[rpoff + n + 1];
  int cnt = dstdeg[t];
  int sfill = cnt > 0 ? srcs[j0] : 0;
  for (int j = j0 + cnt; j < j1; ++j){ srcs[j] = sfill; w[j] = 0.f; }
}

// ---------------- shared device pieces ----------------

template<int FPL, int FinPad>
__device__ __forceinline__ void gather4(const float* __restrict__ gb,
                                        const int* __restrict__ srcs, const float* __restrict__ w,
                                        int j0, int j1, int sub, float* acc){
  #pragma unroll
  for (int q = 0; q < FPL; ++q) acc[q] = 0.f;
  for (int j = j0; j < j1; j += 4){
    i32x4 s4 = *reinterpret_cast<const i32x4*>(srcs + j);
    f32x4 w4 = *reinterpret_cast<const f32x4*>(w + j);
    float v0[FPL], v1[FPL], v2[FPL], v3[FPL];
    vload<FPL>(gb + (size_t)s4.x*FinPad + sub*FPL, v0);
    vload<FPL>(gb + (size_t)s4.y*FinPad + sub*FPL, v1);
    vload<FPL>(gb + (size_t)s4.z*FinPad + sub*FPL, v2);
    vload<FPL>(gb + (size_t)s4.w*FinPad + sub*FPL, v3);
    #pragma unroll
    for (int q = 0; q < FPL; ++q){
      acc[q] = fmaf(w4.x, v0[q], acc[q]);
      acc[q] = fmaf(w4.y, v1[q], acc[q]);
      acc[q] = fmaf(w4.z, v2[q], acc[q]);
      acc[q] = fmaf(w4.w, v3[q], acc[q]);
    }
  }
}

template<int FinPad, int FinReal, int Fout>
__device__ __forceinline__ void gemm_acc(const float* ts, const float* __restrict__ Wk,
                                         int sub, int lanebase, float* o){
  constexpr int FPL = FinPad/4;
  float tv[FinPad];
  #pragma unroll
  for (int s = 0; s < 4; ++s)
    #pragma unroll
    for (int q = 0; q < FPL; ++q)
      tv[s*FPL+q] = __shfl(ts[q], lanebase + s, 64);
  if constexpr (Fout % 4 == 0){
    constexpr int OPL = Fout/4;
    #pragma unroll
    for (int fi = 0; fi < FinReal; ++fi)
      #pragma unroll
      for (int q = 0; q < OPL; ++q)
        o[q] = fmaf(tv[fi], Wk[fi*Fout + sub*OPL + q], o[q]);
  } else {
    if (sub < Fout){
      #pragma unroll
      for (int fi = 0; fi < FinReal; ++fi)
        o[0] = fmaf(tv[fi], Wk[fi*Fout + sub], o[0]);
    }
  }
}

template<int FinPad, int PRE>
__device__ __forceinline__ void pre_row(const float* __restrict__ psrc, const int* __restrict__ pidx,
                                        const float* __restrict__ pw, int n, int g, int Nin, int sub,
                                        float* r){
  constexpr int FPL = FinPad/4;
  if constexpr (PRE == 1){
    int t = g & 15;
    float th = 6.283185307179586f * (float)t / 16.0f;
    float sn, cs; sincosf(th, &sn, &cs);
    const float* xr = psrc + ((size_t)g*16384 + n)*3;
    #pragma unroll
    for (int q = 0; q < FPL; ++q){
      int c = sub*FPL + q;
      float v = 0.f;
      if (c < 6) v = xr[c % 3] * (c < 3 ? cs : sn);
      r[q] = v;
    }
  } else {
    int i0 = pidx[n*3+0], i1 = pidx[n*3+1], i2 = pidx[n*3+2];
    float w0 = pw[n*3+0], w1 = pw[n*3+1], w2 = pw[n*3+2];
    const float* bsrc = psrc + (size_t)g*Nin*FinPad + sub*FPL;
    float a[FPL], b[FPL], c[FPL];
    vload<FPL>(bsrc + (size_t)i0*FinPad, a);
    vload<FPL>(bsrc + (size_t)i1*FinPad, b);
    vload<FPL>(bsrc + (size_t)i2*FinPad, c);
    #pragma unroll
    for (int q = 0; q < FPL; ++q) r[q] = fmaf(w0, a[q], fmaf(w1, b[q], w2*c[q]));
  }
}

// ---------------- cooperative fused level kernel ----------------

template<int FinPad, int FinReal, int Fout, int ITEMS, int PRE>
__global__ void __launch_bounds__(256, 2)
k_cheb_coop(const int* __restrict__ rp, const int* __restrict__ srcs, const float* __restrict__ w,
            const float* __restrict__ psrc, const int* __restrict__ pidx, const float* __restrict__ pw,
            float* __restrict__ bufX, float* __restrict__ bufT1, float* __restrict__ out,
            const float* __restrict__ W6, const float* __restrict__ bias,
            const float* __restrict__ savg,
            int G, int logN, int Nin, int relu){
  constexpr int FPL = FinPad/4;
  constexpr int OPL = (Fout % 4 == 0) ? Fout/4 : 1;
  cg::grid_group gg = cg::this_grid();
  const int tid = threadIdx.x;
  const int bid = blockIdx.x, nb = gridDim.x;
  const int N = 1 << logN;
  const int sub = tid & 3;
  const int lanebase = (tid & 63) & ~3;
  const int vnb = nb * ITEMS;
  const bool doswz = (G == 32) && ((vnb & 31) == 0);

  int ii[ITEMS];
  #pragma unroll
  for (int m = 0; m < ITEMS; ++m){
    int vb;
    if (doswz){
      int vbpg = vnb >> 5;
      int xcd = bid & 7;
      int j = (bid >> 3)*ITEMS + m;
      int gi = j / vbpg, nc = j - gi*vbpg;
      vb = ((gi << 3) | xcd)*vbpg + nc;
    } else vb = bid*ITEMS + m;
    ii[m] = (int)((((long long)vb << 8) + tid) >> 2);
  }

  float oacc[ITEMS][OPL];

  // prologue: T0 rows into bufX
  #pragma unroll
  for (int m = 0; m < ITEMS; ++m){
    int i = ii[m];
    int n = i & (N-1);
    int g = i >> logN;
    float r[FPL];
    pre_row<FinPad,PRE>(psrc, pidx, pw, n, g, Nin, sub, r);
    vstore<FPL>(bufX + (size_t)i*FinPad + sub*FPL, r);
  }
  gg.sync();

  // k=0,1
  #pragma unroll
  for (int m = 0; m < ITEMS; ++m){
    int i = ii[m];
    int n = i & (N-1);
    const float* gb = bufX + (size_t)(i - n)*FinPad;
    float t0[FPL]; vload<FPL>(bufX + (size_t)i*FinPad + sub*FPL, t0);
    float t1[FPL];
    gather4<FPL,FinPad>(gb, srcs, w, rp[n], rp[n+1], sub, t1);
    vstore<FPL>(bufT1 + (size_t)i*FinPad + sub*FPL, t1);
    if constexpr (Fout % 4 == 0){
      #pragma unroll
      for (int q = 0; q < OPL; ++q) oacc[m][q] = bias ? bias[sub*OPL + q] : 0.f;
    } else {
      oacc[m][0] = (bias && sub < Fout) ? bias[sub] : 0.f;
    }
    gemm_acc<FinPad,FinReal,Fout>(t0, W6, sub, lanebase, oacc[m]);
    gemm_acc<FinPad,FinReal,Fout>(t1, W6 + (size_t)FinReal*Fout, sub, lanebase, oacc[m]);
  }
  gg.sync();

  // k=2..4 ping-pong, in-place Tm2 -> Tk
  float* Ab = bufT1;
  float* Bb = bufX;
  for (int k = 2; k <= 4; ++k){
    const float* Wk = W6 + (size_t)k*FinReal*Fout;
    #pragma unroll
    for (int m = 0; m < ITEMS; ++m){
      int i = ii[m];
      int n = i & (N-1);
      const float* gb = Ab + (size_t)(i - n)*FinPad;
      float tk[FPL];
      gather4<FPL,FinPad>(gb, srcs, w, rp[n], rp[n+1], sub, tk);
      float tm2[FPL]; vload<FPL>(Bb + (size_t)i*FinPad + sub*FPL, tm2);
      #pragma unroll
      for (int q = 0; q < FPL; ++q) tk[q] = 2.f*tk[q] - tm2[q];
      vstore<FPL>(Bb + (size_t)i*FinPad + sub*FPL, tk);
      gemm_acc<FinPad,FinReal,Fout>(tk, Wk, sub, lanebase, oacc[m]);
    }
    float* t = Ab; Ab = Bb; Bb = t;
    gg.sync();
  }

  // k=5 epilogue
  {
    const float* Wk = W6 + (size_t)5*FinReal*Fout;
    #pragma unroll
    for (int m = 0; m < ITEMS; ++m){
      int i = ii[m];
      int n = i & (N-1);
      const float* gb = Ab + (size_t)(i - n)*FinPad;
      float tk[FPL];
      gather4<FPL,FinPad>(gb, srcs, w, rp[n], rp[n+1], sub, tk);
      float tm2[FPL]; vload<FPL>(Bb + (size_t)i*FinPad + sub*FPL, tm2);
      #pragma unroll
      for (int q = 0; q < FPL; ++q) tk[q] = 2.f*tk[q] - tm2[q];
      gemm_acc<FinPad,FinReal,Fout>(tk, Wk, sub, lanebase, oacc[m]);
      if constexpr (Fout % 4 == 0){
        float o[OPL];
        #pragma unroll
        for (int q = 0; q < OPL; ++q) o[q] = relu ? fmaxf(oacc[m][q], 0.f) : oacc[m][q];
        vstore<OPL>(out + (size_t)i*Fout + sub*OPL, o);
      } else {
        if (sub < Fout){
          float o = oacc[m][0];
          if (relu) o = fmaxf(o, 0.f);
          if (savg){
            int g = i >> logN;
            int b = g >> 4;
            o += savg[((size_t)b*N + n)*3 + sub];
          }
          out[(size_t)i*Fout + sub] = o;
        }
      }
    }
  }
}

// ---------------- non-coop fallback kernels ----------------

template<int FinPad, int PRE>
__global__ void k_pre_f(const float* __restrict__ psrc, const int* __restrict__ pidx,
                        const float* __restrict__ pw, float* __restrict__ bufX,
                        int G, int logN, int Nin){
  constexpr int FPL = FinPad/4;
  long long i4 = (long long)blockIdx.x*blockDim.x + threadIdx.x;
  if (i4 >= ((long long)G << logN)*4) return;
  int sub = (int)(i4 & 3);
  long long i = i4 >> 2;
  int N = 1 << logN;
  int n = (int)(i & (N-1));
  int g = (int)(i >> logN);
  float r[FPL];
  pre_row<FinPad,PRE>(psrc, pidx, pw, n, g, Nin, sub, r);
  vstore<FPL>(bufX + (size_t)i*FinPad + sub*FPL, r);
}

template<int FinPad, int FinReal, int Fout>
__global__ void k_first_f(const int* __restrict__ rp, const int* __restrict__ srcs, const float* __restrict__ w,
                          const float* __restrict__ bufX, float* __restrict__ bufT1, float* __restrict__ out,
                          const float* __restrict__ W6, const float* __restrict__ bias,
                          int G, int logN){
  constexpr int FPL = FinPad/4;
  constexpr int OPL = (Fout % 4 == 0) ? Fout/4 : 1;
  long long i4 = (long long)blockIdx.x*blockDim.x + threadIdx.x;
  if (i4 >= ((long long)G << logN)*4) return;
  int sub = (int)(i4 & 3);
  long long i = i4 >> 2;
  int N = 1 << logN;
  int n = (int)(i & (N-1));
  int lanebase = ((int)threadIdx.x & 63) & ~3;
  const float* gb = bufX + (size_t)(i - n)*FinPad;
  float t0[FPL]; vload<FPL>(bufX + (size_t)i*FinPad + sub*FPL, t0);
  float t1[FPL];
  gather4<FPL,FinPad>(gb, srcs, w, rp[n], rp[n+1], sub, t1);
  vstore<FPL>(bufT1 + (size_t)i*FinPad + sub*FPL, t1);
  float o[OPL];
  if constexpr (Fout % 4 == 0){
    #pragma unroll
    for (int q = 0; q < OPL; ++q) o[q] = bias ? bias[sub*OPL + q] : 0.f;
  } else {
    o[0] = (bias && sub < Fout) ? bias[sub] : 0.f;
  }
  gemm_acc<FinPad,FinReal,Fout>(t0, W6, sub, lanebase, o);
  gemm_acc<FinPad,FinReal,Fout>(t1, W6 + (size_t)FinReal*Fout, sub, lanebase, o);
  if constexpr (Fout % 4 == 0) vstore<OPL>(out + (size_t)i*Fout + sub*OPL, o);
  else if (sub < Fout) out[(size_t)i*Fout + sub] = o[0];
}

// P holds Tm2, overwritten in-place with Tk (own slice only). last: relu/savg.
template<int FinPad, int FinReal, int Fout>
__global__ void k_step_f(const int* __restrict__ rp, const int* __restrict__ srcs, const float* __restrict__ w,
                         const float* __restrict__ Tm1, float* __restrict__ P, float* __restrict__ out,
                         const float* __restrict__ Wk, const float* __restrict__ savg,
                         int G, int logN, int relu, int last){
  constexpr int FPL = FinPad/4;
  constexpr int OPL = (Fout % 4 == 0) ? Fout/4 : 1;
  long long i4 = (long long)blockIdx.x*blockDim.x + threadIdx.x;
  if (i4 >= ((long long)G << logN)*4) return;
  int sub = (int)(i4 & 3);
  long long i = i4 >> 2;
  int N = 1 << logN;
  int n = (int)(i & (N-1));
  int lanebase = ((int)threadIdx.x & 63) & ~3;
  const float* gb = Tm1 + (size_t)(i - n)*FinPad;
  float tk[FPL];
  gather4<FPL,FinPad>(gb, srcs, w, rp[n], rp[n+1], sub, tk);
  float tm2[FPL]; vload<FPL>(P + (size_t)i*FinPad + sub*FPL, tm2);
  #pragma unroll
  for (int q = 0; q < FPL; ++q) tk[q] = 2.f*tk[q] - tm2[q];
  vstore<FPL>(P + (size_t)i*FinPad + sub*FPL, tk);
  float o[OPL];
  if constexpr (Fout % 4 == 0) vload<OPL>(out + (size_t)i*Fout + sub*OPL, o);
  else { o[0] = (sub < Fout) ? out[(size_t)i*Fout + sub] : 0.f; }
  gemm_acc<FinPad,FinReal,Fout>(tk, Wk, sub, lanebase, o);
  if constexpr (Fout % 4 == 0){
    if (last && relu){
      #pragma unroll
      for (int q = 0; q < OPL; ++q) o[q] = fmaxf(o[q], 0.f);
    }
    vstore<OPL>(out + (size_t)i*Fout + sub*OPL, o);
  } else {
    if (sub < Fout){
      float v = o[0];
      if (last && relu) v = fmaxf(v, 0.f);
      if (last && savg){
        int g = (int)(i >> logN);
        int b = g >> 4;
        v += savg[((size_t)b*N + n)*3 + sub];
      }
      out[(size_t)i*Fout + sub] = v;
    }
  }
}

// ---------------- other model kernels ----------------

template<int F>
__global__ void k_pool_t(const float* __restrict__ X, const int* __restrict__ idx,
                         const float* __restrict__ w, float* __restrict__ out,
                         int G, int Nin, int Nout){
  long long i = (long long)blockIdx.x*blockDim.x + threadIdx.x;
  if (i >= (long long)G*Nout) return;
  int n = (int)(i % Nout), g = (int)(i / Nout);
  int i0 = idx[n*3+0], i1 = idx[n*3+1], i2 = idx[n*3+2];
  float w0 = w[n*3+0], w1 = w[n*3+1], w2 = w[n*3+2];
  const float* b = X + (size_t)g*Nin*F;
  float r0[F], r1[F], r2[F], o[F];
  loadrow<F>(b + (size_t)i0*F, r0);
  loadrow<F>(b + (size_t)i1*F, r1);
  loadrow<F>(b + (size_t)i2*F, r2);
  #pragma unroll
  for (int f = 0; f < F; ++f)
    o[f] = fmaf(w0, r0[f], fmaf(w1, r1[f], w2 * r2[f]));
  storerow<F>(out + ((size_t)g*Nout + n)*F, o);
}

__global__ void k_mu(const float* __restrict__ h, const float* __restrict__ W,
                     const float* __restrict__ b, float* __restrict__ mu){
  int wid = (blockIdx.x*blockDim.x + threadIdx.x) >> 6;
  int lane = threadIdx.x & 63;
  if (wid >= 32*48) return;
  int z = wid % 48, g = wid / 48;
  const float* hr = h + (size_t)g*2048;
  const float* wr = W + (size_t)z*2048;
  float acc = 0.f;
  for (int f = lane; f < 2048; f += 64) acc = fmaf(hr[f], wr[f], acc);
  for (int o = 32; o > 0; o >>= 1) acc += __shfl_down(acc, o, 64);
  if (lane == 0) mu[wid] = acc + b[z];
}

__global__ void k_mucs(const float* __restrict__ mu, float* __restrict__ muc,
                       float* __restrict__ mus, float* __restrict__ out){
  int i = blockIdx.x*blockDim.x + threadIdx.x;
  if (i >= 96) return;
  int z = i % 48, bp = i / 48;
  float acc = 0.f;
  for (int b = 0; b < 2; ++b)
    for (int t = 8*bp; t < 8*bp + 8; ++t)
      acc += mu[(b*16 + t)*48 + z];
  acc *= (1.f/16.f);
  if (z < 32){ muc[bp*32 + z] = acc; out[bp*32 + z] = acc; }
  else       { mus[bp*16 + (z-32)] = acc; out[64 + bp*16 + (z-32)] = acc; }
}

__global__ void k_zin(const float* __restrict__ muc, const float* __restrict__ mus,
                      float* __restrict__ zin){
  int i = blockIdx.x*blockDim.x + threadIdx.x;
  if (i >= 32*64) return;
  int c = i % 64, g = i / 64;
  int b = g / 16, t = g % 16;
  float v;
  if (c < 32){
    v = muc[b*32 + c];
  } else {
    float th = 6.283185307179586f * (float)t / 16.0f;
    int k = c - 32;
    int kk = (k < 16) ? k : (k - 16);
    float m = mus[b*16 + kk];
    v = (k < 16) ? m * cosf(th) : m * sinf(th);
  }
  zin[i] = v;
}

__global__ void k_lin(const float* __restrict__ z, const float* __restrict__ W,
                      const float* __restrict__ b, float* __restrict__ y,
                      int G, int Z, int relu){
  int i = blockIdx.x*blockDim.x + threadIdx.x;
  if (i >= G*2048) return;
  int f = i % 2048, g = i / 2048;
  const float* zr = z + (size_t)g*Z;
  const float* wr = W + (size_t)f*Z;
  float acc = b[f];
  for (int k = 0; k < Z; ++k) acc = fmaf(zr[k], wr[k], acc);
  if (relu) acc = fmaxf(acc, 0.f);
  y[i] = acc;
}

// ---------------- host orchestration ----------------

struct CoopArgs {
  const int* rp; const int* srcs; const float* w;
  const float* psrc; const int* pidx; const float* pw;
  float* bufX; float* bufT1; float* out;
  const float* W6; const float* bias; const float* savg;
  int G; int logN; int Nin; int relu;
};

template<int FinPad, int FinReal, int Fout, int ITEMS, int PRE>
static hipError_t try_coop(hipStream_t s, CoopArgs a){
  long long GN4 = ((long long)a.G << a.logN) * 4;
  if (GN4 % (256LL*ITEMS) != 0) return hipErrorUnknown;
  long long grid = GN4 / (256LL*ITEMS);
  int maxb = 0;
  hipError_t e = hipOccupancyMaxActiveBlocksPerMultiprocessor(
      &maxb, (const void*)k_cheb_coop<FinPad,FinReal,Fout,ITEMS,PRE>, 256, 0);
  if (e != hipSuccess || (long long)maxb * NCU < grid) return hipErrorUnknown;
  void* args[] = {&a.rp,&a.srcs,&a.w,&a.psrc,&a.pidx,&a.pw,&a.bufX,&a.bufT1,&a.out,
                  &a.W6,&a.bias,&a.savg,&a.G,&a.logN,&a.Nin,&a.relu};
  return hipLaunchCooperativeKernel((void*)k_cheb_coop<FinPad,FinReal,Fout,ITEMS,PRE>,
                                    dim3((int)grid), dim3(256), args, 0, s);
}

template<int FinPad, int FinReal, int Fout, int PRE>
static void run_fallback(hipStream_t s, const CoopArgs& a){
  long long GN4 = ((long long)a.G << a.logN) * 4;
  int grid = cdiv(GN4, 256);
  k_pre_f<FinPad,PRE><<<grid,256,0,s>>>(a.psrc, a.pidx, a.pw, a.bufX, a.G, a.logN, a.Nin);
  k_first_f<FinPad,FinReal,Fout><<<grid,256,0,s>>>(a.rp, a.srcs, a.w, a.bufX, a.bufT1, a.out,
                                                   a.W6, a.bias, a.G, a.logN);
  float* Ab = a.bufT1; float* Bb = a.bufX;
  for (int k = 2; k <= 5; ++k){
    int last = (k == 5) ? 1 : 0;
    k_step_f<FinPad,FinReal,Fout><<<grid,256,0,s>>>(a.rp, a.srcs, a.w, Ab, Bb, a.out,
                                                    a.W6 + (size_t)k*FinReal*Fout,
                                                    last ? a.savg : nullptr,
                                                    a.G, a.logN, a.relu, last);
    float* t = Ab; Ab = Bb; Bb = t;
  }
}

template<int FinPad, int FinReal, int Fout, int PRE, int IT1, int IT2>
static void run_level(hipStream_t s, CoopArgs a){
  if (try_coop<FinPad,FinReal,Fout,IT1,PRE>(s, a) == hipSuccess) return;
  if (IT2 != IT1 && try_coop<FinPad,FinReal,Fout,IT2,PRE>(s, a) == hipSuccess) return;
  run_fallback<FinPad,FinReal,Fout,PRE>(s, a);
}

extern "C" void kernel_launch(void* const* d_in, const int* in_sizes, int n_in,
                              void* d_out, int out_size, void* d_ws, size_t ws_size,
                              hipStream_t stream){
  const float* x = (const float*)d_in[0];
  const float* encW[4] = {(const float*)d_in[1],(const float*)d_in[3],(const float*)d_in[5],(const float*)d_in[7]};
  const float* encB[4] = {(const float*)d_in[2],(const float*)d_in[4],(const float*)d_in[6],(const float*)d_in[8]};
  const float* ccW[4]  = {(const float*)d_in[9],(const float*)d_in[11],(const float*)d_in[13],(const float*)d_in[15]};
  const float* ccB[3]  = {(const float*)d_in[10],(const float*)d_in[12],(const float*)d_in[14]};
  const float* csW[4]  = {(const float*)d_in[16],(const float*)d_in[18],(const float*)d_in[20],(const float*)d_in[22]};
  const float* csB[3]  = {(const float*)d_in[17],(const float*)d_in[19],(const float*)d_in[21]};
  const float* muW  = (const float*)d_in[23]; const float* muB  = (const float*)d_in[24];
  const float* lincW = (const float*)d_in[25]; const float* lincB = (const float*)d_in[26];
  const float* linsW = (const float*)d_in[27]; const float* linsB = (const float*)d_in[28];
  const int* ei[5] = {(const int*)d_in[29],(const int*)d_in[30],(const int*)d_in[31],
                      (const int*)d_in[32],(const int*)d_in[33]};
  const int* ds_i[4]; const float* ds_w[4]; const int* us_i[4]; const float* us_w[4];
  for (int l = 0; l < 4; ++l){
    ds_i[l] = (const int*)d_in[34 + 4*l]; ds_w[l] = (const float*)d_in[35 + 4*l];
    us_i[l] = (const int*)d_in[36 + 4*l]; us_w[l] = (const float*)d_in[37 + 4*l];
  }

  float* ws = (float*)d_ws;
  const size_t BIG = 8388608;
  float* B0 = ws + 0*BIG;
  float* B1 = ws + 1*BIG;
  float* B2 = ws + 2*BIG;
  float* B3 = ws + 3*BIG;
  size_t off = 4*BIG;

  int*   rp_all     = (int*)(ws + off); off += RPTOT;
  int*   cursor_all = (int*)(ws + off); off += RPTOT;
  off = (off + 3) & ~(size_t)3;
  int*   srcs_all   = (int*)(ws + off); off += CTOT;
  float* w_all      =        ws + off;  off += CTOT;
  int*   rowdeg     = (int*)(ws + off); off += NTOT;
  int*   dstdeg     = (int*)(ws + off); off += NTOT;
  float* dis        =        ws + off;  off += NTOT;
  float* hmu        =        ws + off;  off += (size_t)32*2048;
  float* mu         =        ws + off;  off += (size_t)32*48;
  float* muc        =        ws + off;  off += 64;
  float* mus        =        ws + off;  off += 32;
  float* zin        =        ws + off;  off += (size_t)32*64;

  float* outp = (float*)d_out;
  float* out_savg = outp + 96;
  float* out_st   = outp + 96 + 98304;

  // ---- CSR build ----
  hipMemsetAsync(rowdeg, 0, 2*(size_t)NTOT*sizeof(int), stream);
  k_degs_all<<<cdiv(ETOT,TPB),TPB,0,stream>>>(ei[0],ei[1],ei[2],ei[3],ei[4], rowdeg, dstdeg);
  k_dis_all<<<cdiv(NTOT,TPB),TPB,0,stream>>>(rowdeg, dis);
  k_scan5<<<5,256,0,stream>>>(dstdeg, rp_all, cursor_all);
  k_fill_all<<<cdiv(ETOT,TPB),TPB,0,stream>>>(ei[0],ei[1],ei[2],ei[3],ei[4], dis, cursor_all, srcs_all, w_all);
  k_pad_all<<<cdiv(NTOT,TPB),TPB,0,stream>>>(dstdeg, rp_all, srcs_all, w_all);

  const int RPOFF[5] = {0,16385,20482,21507,21764};
  const int* RP[5];
  for (int l = 0; l < 5; ++l) RP[l] = rp_all + RPOFF[l];

  // ---- encoder ----
  run_level<8,6,16,1,8,16>(stream, {RP[0],srcs_all,w_all, x,nullptr,nullptr,
                                    B0,B1,B2, encW[0],encB[0],nullptr, 32,14,0,1});
  run_level<16,16,16,0,2,4>(stream, {RP[1],srcs_all,w_all, B2,ds_i[0],ds_w[0],
                                     B0,B1,B3, encW[1],encB[1],nullptr, 32,12,16384,1});
  run_level<16,16,16,0,1,2>(stream, {RP[2],srcs_all,w_all, B3,ds_i[1],ds_w[1],
                                     B0,B1,B2, encW[2],encB[2],nullptr, 32,10,4096,1});
  run_level<16,16,32,0,1,1>(stream, {RP[3],srcs_all,w_all, B2,ds_i[2],ds_w[2],
                                     B0,B1,B3, encW[3],encB[3],nullptr, 32,8,1024,1});
  k_pool_t<32><<<cdiv((long long)32*64,TPB),TPB,0,stream>>>(B3, ds_i[3], ds_w[3], hmu, 32, 256, 64);

  // ---- latent ----
  k_mu<<<cdiv((long long)32*48*64,TPB),TPB,0,stream>>>(hmu, muW, muB, mu);
  k_mucs<<<1,128,0,stream>>>(mu, muc, mus, outp);

  // ---- decoder c (G=2) ----
  k_lin<<<cdiv((long long)2*2048,TPB),TPB,0,stream>>>(muc, lincW, lincB, B2, 2, 32, 0);
  run_level<32,32,16,0,1,1>(stream, {RP[3],srcs_all,w_all, B2,us_i[3],us_w[3],
                                     B0,B1,B3, ccW[0],ccB[0],nullptr, 2,8,64,1});
  run_level<16,16,16,0,1,1>(stream, {RP[2],srcs_all,w_all, B3,us_i[2],us_w[2],
                                     B0,B1,B2, ccW[1],ccB[1],nullptr, 2,10,256,1});
  run_level<16,16,16,0,1,1>(stream, {RP[1],srcs_all,w_all, B2,us_i[1],us_w[1],
                                     B0,B1,B3, ccW[2],ccB[2],nullptr, 2,12,1024,1});
  run_level<16,16,3,0,1,1>(stream, {RP[4],srcs_all,w_all, B3,us_i[0],us_w[0],
                                    B0,B1,out_savg, ccW[3],nullptr,nullptr, 2,14,4096,0});

  // ---- decoder s (G=32) ----
  k_zin<<<cdiv(32*64,TPB),TPB,0,stream>>>(muc, mus, zin);
  k_lin<<<cdiv((long long)32*2048,TPB),TPB,0,stream>>>(zin, linsW, linsB, B2, 32, 64, 1);
  run_level<32,32,16,0,1,1>(stream, {RP[3],srcs_all,w_all, B2,us_i[3],us_w[3],
                                     B0,B1,B3, csW[0],csB[0],nullptr, 32,8,64,1});
  run_level<16,16,16,0,1,2>(stream, {RP[2],srcs_all,w_all, B3,us_i[2],us_w[2],
                                     B0,B1,B2, csW[1],csB[1],nullptr, 32,10,256,1});
  run_level<16,16,16,0,2,4>(stream, {RP[1],srcs_all,w_all, B2,us_i[1],us_w[1],
                                     B0,B1,B3, csW[2],csB[2],nullptr, 32,12,1024,1});
  run_level<16,16,3,0,8,16>(stream, {RP[4],srcs_all,w_all, B3,us_i[0],us_w[0],
                                     B0,B1,out_st, csW[3],nullptr,out_savg, 32,14,4096,0});

  (void)in_sizes; (void)n_in; (void)out_size; (void)ws_size;
}

// Round 11
// 1325.811 us; speedup vs baseline: 1.9742x; 1.9742x over previous
//
#include <hip/hip_runtime.h>
#include <cstdint>
#include <cstddef>

#define TPB 256

typedef float f32x4 __attribute__((ext_vector_type(4)));
typedef float f32x2 __attribute__((ext_vector_type(2)));
typedef int   i32x4 __attribute__((ext_vector_type(4)));

static inline int cdiv(long long a, int b){ return (int)((a + (long long)b - 1) / b); }

// ---- concat level tables: N={16384,4096,1024,256,16384}, E={196608,49152,12288,3072,196608}
// NOFF={0,16384,20480,21504,21760} NTOT=38144
// CSR cap = E+8N -> COFF={0,327680,409600,430080,435200}, CTOT=762880
#define NTOT 38144
#define ETOT 457728
#define CTOT 762880
#define RPTOT 38149

// ---------------- small vector helpers ----------------

template<int W>
__device__ __forceinline__ void vload(const float* __restrict__ p, float* r){
  if constexpr (W == 8){ vload<4>(p, r); vload<4>(p+4, r+4); }
  else if constexpr (W == 4){ f32x4 v = *reinterpret_cast<const f32x4*>(p); r[0]=v.x;r[1]=v.y;r[2]=v.z;r[3]=v.w; }
  else { f32x2 v = *reinterpret_cast<const f32x2*>(p); r[0]=v.x;r[1]=v.y; }
}
template<int W>
__device__ __forceinline__ void vstore(float* __restrict__ p, const float* r){
  if constexpr (W == 8){ vstore<4>(p, r); vstore<4>(p+4, r+4); }
  else if constexpr (W == 4){ f32x4 v; v.x=r[0];v.y=r[1];v.z=r[2];v.w=r[3]; *reinterpret_cast<f32x4*>(p) = v; }
  else { f32x2 v; v.x=r[0];v.y=r[1]; *reinterpret_cast<f32x2*>(p) = v; }
}

template<int F>
__device__ __forceinline__ void loadrow(const float* __restrict__ p, float* r){
  #pragma unroll
  for (int q = 0; q < F/4; ++q) vload<4>(p + 4*q, r + 4*q);
}
template<int F>
__device__ __forceinline__ void storerow(float* __restrict__ p, const float* r){
  #pragma unroll
  for (int q = 0; q < F/4; ++q) vstore<4>(p + 4*q, r + 4*q);
}

// ---------------- CSR build (fused across 5 levels, rows padded to x8) ----------------

__device__ __forceinline__ bool lvl_edge(int t, const int* e0,const int* e1,const int* e2,const int* e3,const int* e4,
                                         const int*& ei, int& E, int& noff, int& rpoff, int& rel){
  if (t < 196608){ ei=e0; E=196608; noff=0;     rpoff=0;     rel=t;        return true; }
  if (t < 245760){ ei=e1; E=49152;  noff=16384; rpoff=16385; rel=t-196608; return true; }
  if (t < 258048){ ei=e2; E=12288;  noff=20480; rpoff=20482; rel=t-245760; return true; }
  if (t < 261120){ ei=e3; E=3072;   noff=21504; rpoff=21507; rel=t-258048; return true; }
  if (t < 457728){ ei=e4; E=196608; noff=21760; rpoff=21764; rel=t-261120; return true; }
  return false;
}

__global__ void k_degs_all(const int* e0,const int* e1,const int* e2,const int* e3,const int* e4,
                           int* __restrict__ rowdeg, int* __restrict__ dstdeg){
  int t = blockIdx.x*blockDim.x + threadIdx.x;
  const int* ei; int E, noff, rpoff, rel;
  if (!lvl_edge(t, e0,e1,e2,e3,e4, ei,E,noff,rpoff,rel)) return;
  atomicAdd(&rowdeg[noff + ei[rel]], 1);
  atomicAdd(&dstdeg[noff + ei[E + rel]], 1);
}

__global__ void k_dis_all(const int* __restrict__ rowdeg, float* __restrict__ dis){
  int t = blockIdx.x*blockDim.x + threadIdx.x;
  if (t >= NTOT) return;
  int d = rowdeg[t];
  dis[t] = d > 0 ? rsqrtf((float)d) : 0.f;
}

__global__ void k_scan5(const int* __restrict__ dstdeg, int* __restrict__ rp, int* __restrict__ cursor){
  const int NnA[5]  = {16384,4096,1024,256,16384};
  const int NOFF[5] = {0,16384,20480,21504,21760};
  const int COFF[5] = {0,327680,409600,430080,435200};
  __shared__ int part[257];
  int l = blockIdx.x;
  int N = NnA[l];
  const int* cnt = dstdeg + NOFF[l];
  int* rpl = rp + NOFF[l] + l;
  int* cul = cursor + NOFF[l] + l;
  int tid = threadIdx.x;
  int chunk = (N + 255) / 256;
  int lo = tid*chunk; if (lo > N) lo = N;
  int hi = lo + chunk; if (hi > N) hi = N;
  int s = 0;
  for (int i = lo; i < hi; ++i) s += (cnt[i] + 7) & ~7;
  part[tid+1] = s;
  if (tid == 0) part[0] = COFF[l];
  __syncthreads();
  if (tid == 0){ for (int i = 1; i <= 256; ++i) part[i] += part[i-1]; }
  __syncthreads();
  int run = part[tid];
  for (int i = lo; i < hi; ++i){ rpl[i] = run; cul[i] = run; run += (cnt[i] + 7) & ~7; }
  if (tid == 0) rpl[N] = part[256];
}

__global__ void k_fill_all(const int* e0,const int* e1,const int* e2,const int* e3,const int* e4,
                           const float* __restrict__ dis, int* __restrict__ cursor,
                           int* __restrict__ srcs, float* __restrict__ w){
  int t = blockIdx.x*blockDim.x + threadIdx.x;
  const int* ei; int E, noff, rpoff, rel;
  if (!lvl_edge(t, e0,e1,e2,e3,e4, ei,E,noff,rpoff,rel)) return;
  int src = ei[rel], dst = ei[E + rel];
  int pos = atomicAdd(&cursor[rpoff + dst], 1);
  srcs[pos] = src;
  w[pos] = dis[noff + src] * dis[noff + dst];
}

__global__ void k_pad_all(const int* __restrict__ dstdeg, const int* __restrict__ rp,
                          int* __restrict__ srcs, float* __restrict__ w){
  int t = blockIdx.x*blockDim.x + threadIdx.x;
  if (t >= NTOT) return;
  int rpoff, n;
  if      (t < 16384){ rpoff = 0;     n = t; }
  else if (t < 20480){ rpoff = 16385; n = t - 16384; }
  else if (t < 21504){ rpoff = 20482; n = t - 20480; }
  else if (t < 21760){ rpoff = 21507; n = t - 21504; }
  else               { rpoff = 21764; n = t - 21760; }
  int j0 = rp[rpoff + n];
  int j1 = rp[rpoff + n + 1];
  int cnt = dstdeg[t];
  int sfill = cnt > 0 ? srcs[j0] : 0;
  for (int j = j0 + cnt; j < j1; ++j){ srcs[j] = sfill; w[j] = 0.f; }
}

// ---------------- shared device pieces ----------------

// 8 independent gathers per iteration (rows padded to x8)
template<int FPL, int FinPad>
__device__ __forceinline__ void gather8(const float* __restrict__ gb,
                                        const int* __restrict__ srcs, const float* __restrict__ w,
                                        int j0, int j1, int sub, float* acc){
  #pragma unroll
  for (int q = 0; q < FPL; ++q) acc[q] = 0.f;
  for (int j = j0; j < j1; j += 8){
    i32x4 sa = *reinterpret_cast<const i32x4*>(srcs + j);
    i32x4 sb = *reinterpret_cast<const i32x4*>(srcs + j + 4);
    f32x4 wa = *reinterpret_cast<const f32x4*>(w + j);
    f32x4 wb = *reinterpret_cast<const f32x4*>(w + j + 4);
    float v0[FPL], v1[FPL], v2[FPL], v3[FPL], v4[FPL], v5[FPL], v6[FPL], v7[FPL];
    vload<FPL>(gb + (size_t)sa.x*FinPad + sub*FPL, v0);
    vload<FPL>(gb + (size_t)sa.y*FinPad + sub*FPL, v1);
    vload<FPL>(gb + (size_t)sa.z*FinPad + sub*FPL, v2);
    vload<FPL>(gb + (size_t)sa.w*FinPad + sub*FPL, v3);
    vload<FPL>(gb + (size_t)sb.x*FinPad + sub*FPL, v4);
    vload<FPL>(gb + (size_t)sb.y*FinPad + sub*FPL, v5);
    vload<FPL>(gb + (size_t)sb.z*FinPad + sub*FPL, v6);
    vload<FPL>(gb + (size_t)sb.w*FinPad + sub*FPL, v7);
    #pragma unroll
    for (int q = 0; q < FPL; ++q){
      acc[q] = fmaf(wa.x, v0[q], acc[q]);
      acc[q] = fmaf(wa.y, v1[q], acc[q]);
      acc[q] = fmaf(wa.z, v2[q], acc[q]);
      acc[q] = fmaf(wa.w, v3[q], acc[q]);
      acc[q] = fmaf(wb.x, v4[q], acc[q]);
      acc[q] = fmaf(wb.y, v5[q], acc[q]);
      acc[q] = fmaf(wb.z, v6[q], acc[q]);
      acc[q] = fmaf(wb.w, v7[q], acc[q]);
    }
  }
}

template<int FinPad, int FinReal, int Fout>
__device__ __forceinline__ void gemm_acc(const float* ts, const float* __restrict__ Wk,
                                         int sub, int lanebase, float* o){
  constexpr int FPL = FinPad/4;
  float tv[FinPad];
  #pragma unroll
  for (int s = 0; s < 4; ++s)
    #pragma unroll
    for (int q = 0; q < FPL; ++q)
      tv[s*FPL+q] = __shfl(ts[q], lanebase + s, 64);
  if constexpr (Fout % 4 == 0){
    constexpr int OPL = Fout/4;
    #pragma unroll
    for (int fi = 0; fi < FinReal; ++fi)
      #pragma unroll
      for (int q = 0; q < OPL; ++q)
        o[q] = fmaf(tv[fi], Wk[fi*Fout + sub*OPL + q], o[q]);
  } else {
    if (sub < Fout){
      #pragma unroll
      for (int fi = 0; fi < FinReal; ++fi)
        o[0] = fmaf(tv[fi], Wk[fi*Fout + sub], o[0]);
    }
  }
}

// XCD-aware index swizzle (G==32 grids): pin g-slices to XCDs for L2 locality
__device__ __forceinline__ long long swz_i(int G){
  int bid = blockIdx.x, nb = gridDim.x;
  if (G == 32 && (nb & 31) == 0){
    int bpg = nb >> 5;
    int xcd = bid & 7, j = bid >> 3;
    int gi = j / bpg, nc = j - gi*bpg;
    bid = ((gi << 3) | xcd) * bpg + nc;
  }
  return (long long)bid * blockDim.x + threadIdx.x;
}

template<int FinPad, int PRE>
__device__ __forceinline__ void pre_row(const float* __restrict__ psrc, const int* __restrict__ pidx,
                                        const float* __restrict__ pw, int n, int g, int Nin, int sub,
                                        float* r){
  constexpr int FPL = FinPad/4;
  if constexpr (PRE == 1){
    int t = g & 15;
    float th = 6.283185307179586f * (float)t / 16.0f;
    float sn, cs; sincosf(th, &sn, &cs);
    const float* xr = psrc + ((size_t)g*16384 + n)*3;
    #pragma unroll
    for (int q = 0; q < FPL; ++q){
      int c = sub*FPL + q;
      float v = 0.f;
      if (c < 6) v = xr[c % 3] * (c < 3 ? cs : sn);
      r[q] = v;
    }
  } else {
    int i0 = pidx[n*3+0], i1 = pidx[n*3+1], i2 = pidx[n*3+2];
    float w0 = pw[n*3+0], w1 = pw[n*3+1], w2 = pw[n*3+2];
    const float* bsrc = psrc + (size_t)g*Nin*FinPad + sub*FPL;
    float a[FPL], b[FPL], c[FPL];
    vload<FPL>(bsrc + (size_t)i0*FinPad, a);
    vload<FPL>(bsrc + (size_t)i1*FinPad, b);
    vload<FPL>(bsrc + (size_t)i2*FinPad, c);
    #pragma unroll
    for (int q = 0; q < FPL; ++q) r[q] = fmaf(w0, a[q], fmaf(w1, b[q], w2*c[q]));
  }
}

// ---------------- Cheb level kernels (non-coop, 4-lane/row) ----------------

template<int FinPad, int PRE>
__global__ void k_pre_f(const float* __restrict__ psrc, const int* __restrict__ pidx,
                        const float* __restrict__ pw, float* __restrict__ bufX,
                        int G, int logN, int Nin){
  constexpr int FPL = FinPad/4;
  long long i4 = swz_i(G);
  if (i4 >= ((long long)G << logN)*4) return;
  int sub = (int)(i4 & 3);
  long long i = i4 >> 2;
  int N = 1 << logN;
  int n = (int)(i & (N-1));
  int g = (int)(i >> logN);
  float r[FPL];
  pre_row<FinPad,PRE>(psrc, pidx, pw, n, g, Nin, sub, r);
  vstore<FPL>(bufX + (size_t)i*FinPad + sub*FPL, r);
}

template<int FinPad, int FinReal, int Fout>
__global__ void k_first_f(const int* __restrict__ rp, const int* __restrict__ srcs, const float* __restrict__ w,
                          const float* __restrict__ bufX, float* __restrict__ bufT1, float* __restrict__ out,
                          const float* __restrict__ W6, const float* __restrict__ bias,
                          int G, int logN){
  constexpr int FPL = FinPad/4;
  constexpr int OPL = (Fout % 4 == 0) ? Fout/4 : 1;
  long long i4 = swz_i(G);
  if (i4 >= ((long long)G << logN)*4) return;
  int sub = (int)(i4 & 3);
  long long i = i4 >> 2;
  int N = 1 << logN;
  int n = (int)(i & (N-1));
  int lanebase = ((int)threadIdx.x & 63) & ~3;
  const float* gb = bufX + (size_t)(i - n)*FinPad;
  float t0[FPL]; vload<FPL>(bufX + (size_t)i*FinPad + sub*FPL, t0);
  float t1[FPL];
  gather8<FPL,FinPad>(gb, srcs, w, rp[n], rp[n+1], sub, t1);
  vstore<FPL>(bufT1 + (size_t)i*FinPad + sub*FPL, t1);
  float o[OPL];
  if constexpr (Fout % 4 == 0){
    #pragma unroll
    for (int q = 0; q < OPL; ++q) o[q] = bias ? bias[sub*OPL + q] : 0.f;
  } else {
    o[0] = (bias && sub < Fout) ? bias[sub] : 0.f;
  }
  gemm_acc<FinPad,FinReal,Fout>(t0, W6, sub, lanebase, o);
  gemm_acc<FinPad,FinReal,Fout>(t1, W6 + (size_t)FinReal*Fout, sub, lanebase, o);
  if constexpr (Fout % 4 == 0) vstore<OPL>(out + (size_t)i*Fout + sub*OPL, o);
  else if (sub < Fout) out[(size_t)i*Fout + sub] = o[0];
}

// P holds Tm2; overwritten in-place with Tk (own slice) unless last.
template<int FinPad, int FinReal, int Fout>
__global__ void k_step_f(const int* __restrict__ rp, const int* __restrict__ srcs, const float* __restrict__ w,
                         const float* __restrict__ Tm1, float* __restrict__ P, float* __restrict__ out,
                         const float* __restrict__ Wk, const float* __restrict__ savg,
                         int G, int logN, int relu, int last){
  constexpr int FPL = FinPad/4;
  constexpr int OPL = (Fout % 4 == 0) ? Fout/4 : 1;
  long long i4 = swz_i(G);
  if (i4 >= ((long long)G << logN)*4) return;
  int sub = (int)(i4 & 3);
  long long i = i4 >> 2;
  int N = 1 << logN;
  int n = (int)(i & (N-1));
  int lanebase = ((int)threadIdx.x & 63) & ~3;
  const float* gb = Tm1 + (size_t)(i - n)*FinPad;
  float tk[FPL];
  gather8<FPL,FinPad>(gb, srcs, w, rp[n], rp[n+1], sub, tk);
  float tm2[FPL]; vload<FPL>(P + (size_t)i*FinPad + sub*FPL, tm2);
  #pragma unroll
  for (int q = 0; q < FPL; ++q) tk[q] = 2.f*tk[q] - tm2[q];
  if (!last) vstore<FPL>(P + (size_t)i*FinPad + sub*FPL, tk);
  float o[OPL];
  if constexpr (Fout % 4 == 0) vload<OPL>(out + (size_t)i*Fout + sub*OPL, o);
  else { o[0] = (sub < Fout) ? out[(size_t)i*Fout + sub] : 0.f; }
  gemm_acc<FinPad,FinReal,Fout>(tk, Wk, sub, lanebase, o);
  if constexpr (Fout % 4 == 0){
    if (last && relu){
      #pragma unroll
      for (int q = 0; q < OPL; ++q) o[q] = fmaxf(o[q], 0.f);
    }
    vstore<OPL>(out + (size_t)i*Fout + sub*OPL, o);
  } else {
    if (sub < Fout){
      float v = o[0];
      if (last && relu) v = fmaxf(v, 0.f);
      if (last && savg){
        int g = (int)(i >> logN);
        int b = g >> 4;
        v += savg[((size_t)b*N + n)*3 + sub];
      }
      out[(size_t)i*Fout + sub] = v;
    }
  }
}

// ---------------- other model kernels ----------------

template<int F>
__global__ void k_pool_t(const float* __restrict__ X, const int* __restrict__ idx,
                         const float* __restrict__ w, float* __restrict__ out,
                         int G, int Nin, int Nout){
  long long i = (long long)blockIdx.x*blockDim.x + threadIdx.x;
  if (i >= (long long)G*Nout) return;
  int n = (int)(i % Nout), g = (int)(i / Nout);
  int i0 = idx[n*3+0], i1 = idx[n*3+1], i2 = idx[n*3+2];
  float w0 = w[n*3+0], w1 = w[n*3+1], w2 = w[n*3+2];
  const float* b = X + (size_t)g*Nin*F;
  float r0[F], r1[F], r2[F], o[F];
  loadrow<F>(b + (size_t)i0*F, r0);
  loadrow<F>(b + (size_t)i1*F, r1);
  loadrow<F>(b + (size_t)i2*F, r2);
  #pragma unroll
  for (int f = 0; f < F; ++f)
    o[f] = fmaf(w0, r0[f], fmaf(w1, r1[f], w2 * r2[f]));
  storerow<F>(out + ((size_t)g*Nout + n)*F, o);
}

__global__ void k_mu(const float* __restrict__ h, const float* __restrict__ W,
                     const float* __restrict__ b, float* __restrict__ mu){
  int wid = (blockIdx.x*blockDim.x + threadIdx.x) >> 6;
  int lane = threadIdx.x & 63;
  if (wid >= 32*48) return;
  int z = wid % 48, g = wid / 48;
  const float* hr = h + (size_t)g*2048;
  const float* wr = W + (size_t)z*2048;
  float acc = 0.f;
  for (int f = lane; f < 2048; f += 64) acc = fmaf(hr[f], wr[f], acc);
  for (int o = 32; o > 0; o >>= 1) acc += __shfl_down(acc, o, 64);
  if (lane == 0) mu[wid] = acc + b[z];
}

__global__ void k_mucs(const float* __restrict__ mu, float* __restrict__ muc,
                       float* __restrict__ mus, float* __restrict__ out){
  int i = blockIdx.x*blockDim.x + threadIdx.x;
  if (i >= 96) return;
  int z = i % 48, bp = i / 48;
  float acc = 0.f;
  for (int b = 0; b < 2; ++b)
    for (int t = 8*bp; t < 8*bp + 8; ++t)
      acc += mu[(b*16 + t)*48 + z];
  acc *= (1.f/16.f);
  if (z < 32){ muc[bp*32 + z] = acc; out[bp*32 + z] = acc; }
  else       { mus[bp*16 + (z-32)] = acc; out[64 + bp*16 + (z-32)] = acc; }
}

__global__ void k_zin(const float* __restrict__ muc, const float* __restrict__ mus,
                      float* __restrict__ zin){
  int i = blockIdx.x*blockDim.x + threadIdx.x;
  if (i >= 32*64) return;
  int c = i % 64, g = i / 64;
  int b = g / 16, t = g % 16;
  float v;
  if (c < 32){
    v = muc[b*32 + c];
  } else {
    float th = 6.283185307179586f * (float)t / 16.0f;
    int k = c - 32;
    int kk = (k < 16) ? k : (k - 16);
    float m = mus[b*16 + kk];
    v = (k < 16) ? m * cosf(th) : m * sinf(th);
  }
  zin[i] = v;
}

__global__ void k_lin(const float* __restrict__ z, const float* __restrict__ W,
                      const float* __restrict__ b, float* __restrict__ y,
                      int G, int Z, int relu){
  int i = blockIdx.x*blockDim.x + threadIdx.x;
  if (i >= G*2048) return;
  int f = i % 2048, g = i / 2048;
  const float* zr = z + (size_t)g*Z;
  const float* wr = W + (size_t)f*Z;
  float acc = b[f];
  for (int k = 0; k < Z; ++k) acc = fmaf(zr[k], wr[k], acc);
  if (relu) acc = fmaxf(acc, 0.f);
  y[i] = acc;
}

// ---------------- host orchestration ----------------

struct LvlArgs {
  const int* rp; const int* srcs; const float* w;
  const float* psrc; const int* pidx; const float* pw;
  float* bufX; float* bufT1; float* out;
  const float* W6; const float* bias; const float* savg;
  int G; int logN; int Nin; int relu;
};

template<int FinPad, int FinReal, int Fout, int PRE>
static void run_level(hipStream_t s, const LvlArgs& a){
  long long GN4 = ((long long)a.G << a.logN) * 4;
  int grid = cdiv(GN4, 256);
  k_pre_f<FinPad,PRE><<<grid,256,0,s>>>(a.psrc, a.pidx, a.pw, a.bufX, a.G, a.logN, a.Nin);
  k_first_f<FinPad,FinReal,Fout><<<grid,256,0,s>>>(a.rp, a.srcs, a.w, a.bufX, a.bufT1, a.out,
                                                   a.W6, a.bias, a.G, a.logN);
  float* Ab = a.bufT1; float* Bb = a.bufX;
  for (int k = 2; k <= 5; ++k){
    int last = (k == 5) ? 1 : 0;
    k_step_f<FinPad,FinReal,Fout><<<grid,256,0,s>>>(a.rp, a.srcs, a.w, Ab, Bb, a.out,
                                                    a.W6 + (size_t)k*FinReal*Fout,
                                                    last ? a.savg : nullptr,
                                                    a.G, a.logN, a.relu, last);
    float* t = Ab; Ab = Bb; Bb = t;
  }
}

extern "C" void kernel_launch(void* const* d_in, const int* in_sizes, int n_in,
                              void* d_out, int out_size, void* d_ws, size_t ws_size,
                              hipStream_t stream){
  const float* x = (const float*)d_in[0];
  const float* encW[4] = {(const float*)d_in[1],(const float*)d_in[3],(const float*)d_in[5],(const float*)d_in[7]};
  const float* encB[4] = {(const float*)d_in[2],(const float*)d_in[4],(const float*)d_in[6],(const float*)d_in[8]};
  const float* ccW[4]  = {(const float*)d_in[9],(const float*)d_in[11],(const float*)d_in[13],(const float*)d_in[15]};
  const float* ccB[3]  = {(const float*)d_in[10],(const float*)d_in[12],(const float*)d_in[14]};
  const float* csW[4]  = {(const float*)d_in[16],(const float*)d_in[18],(const float*)d_in[20],(const float*)d_in[22]};
  const float* csB[3]  = {(const float*)d_in[17],(const float*)d_in[19],(const float*)d_in[21]};
  const float* muW  = (const float*)d_in[23]; const float* muB  = (const float*)d_in[24];
  const float* lincW = (const float*)d_in[25]; const float* lincB = (const float*)d_in[26];
  const float* linsW = (const float*)d_in[27]; const float* linsB = (const float*)d_in[28];
  const int* ei[5] = {(const int*)d_in[29],(const int*)d_in[30],(const int*)d_in[31],
                      (const int*)d_in[32],(const int*)d_in[33]};
  const int* ds_i[4]; const float* ds_w[4]; const int* us_i[4]; const float* us_w[4];
  for (int l = 0; l < 4; ++l){
    ds_i[l] = (const int*)d_in[34 + 4*l]; ds_w[l] = (const float*)d_in[35 + 4*l];
    us_i[l] = (const int*)d_in[36 + 4*l]; us_w[l] = (const float*)d_in[37 + 4*l];
  }

  float* ws = (float*)d_ws;
  const size_t BIG = 8388608;
  float* B0 = ws + 0*BIG;
  float* B1 = ws + 1*BIG;
  float* B2 = ws + 2*BIG;
  float* B3 = ws + 3*BIG;
  size_t off = 4*BIG;

  int*   rp_all     = (int*)(ws + off); off += RPTOT;
  int*   cursor_all = (int*)(ws + off); off += RPTOT;
  off = (off + 3) & ~(size_t)3;
  int*   srcs_all   = (int*)(ws + off); off += CTOT;
  float* w_all      =        ws + off;  off += CTOT;
  int*   rowdeg     = (int*)(ws + off); off += NTOT;
  int*   dstdeg     = (int*)(ws + off); off += NTOT;
  float* dis        =        ws + off;  off += NTOT;
  float* hmu        =        ws + off;  off += (size_t)32*2048;
  float* mu         =        ws + off;  off += (size_t)32*48;
  float* muc        =        ws + off;  off += 64;
  float* mus        =        ws + off;  off += 32;
  float* zin        =        ws + off;  off += (size_t)32*64;

  float* outp = (float*)d_out;
  float* out_savg = outp + 96;
  float* out_st   = outp + 96 + 98304;

  // ---- CSR build (6 dispatches) ----
  hipMemsetAsync(rowdeg, 0, 2*(size_t)NTOT*sizeof(int), stream);
  k_degs_all<<<cdiv(ETOT,TPB),TPB,0,stream>>>(ei[0],ei[1],ei[2],ei[3],ei[4], rowdeg, dstdeg);
  k_dis_all<<<cdiv(NTOT,TPB),TPB,0,stream>>>(rowdeg, dis);
  k_scan5<<<5,256,0,stream>>>(dstdeg, rp_all, cursor_all);
  k_fill_all<<<cdiv(ETOT,TPB),TPB,0,stream>>>(ei[0],ei[1],ei[2],ei[3],ei[4], dis, cursor_all, srcs_all, w_all);
  k_pad_all<<<cdiv(NTOT,TPB),TPB,0,stream>>>(dstdeg, rp_all, srcs_all, w_all);

  const int RPOFF[5] = {0,16385,20482,21507,21764};
  const int* RP[5];
  for (int l = 0; l < 5; ++l) RP[l] = rp_all + RPOFF[l];

  // ---- encoder ----
  run_level<8,6,16,1>(stream, {RP[0],srcs_all,w_all, x,nullptr,nullptr,
                               B0,B1,B2, encW[0],encB[0],nullptr, 32,14,0,1});
  run_level<16,16,16,0>(stream, {RP[1],srcs_all,w_all, B2,ds_i[0],ds_w[0],
                                 B0,B1,B3, encW[1],encB[1],nullptr, 32,12,16384,1});
  run_level<16,16,16,0>(stream, {RP[2],srcs_all,w_all, B3,ds_i[1],ds_w[1],
                                 B0,B1,B2, encW[2],encB[2],nullptr, 32,10,4096,1});
  run_level<16,16,32,0>(stream, {RP[3],srcs_all,w_all, B2,ds_i[2],ds_w[2],
                                 B0,B1,B3, encW[3],encB[3],nullptr, 32,8,1024,1});
  k_pool_t<32><<<cdiv((long long)32*64,TPB),TPB,0,stream>>>(B3, ds_i[3], ds_w[3], hmu, 32, 256, 64);

  // ---- latent ----
  k_mu<<<cdiv((long long)32*48*64,TPB),TPB,0,stream>>>(hmu, muW, muB, mu);
  k_mucs<<<1,128,0,stream>>>(mu, muc, mus, outp);

  // ---- decoder c (G=2) ----
  k_lin<<<cdiv((long long)2*2048,TPB),TPB,0,stream>>>(muc, lincW, lincB, B2, 2, 32, 0);
  run_level<32,32,16,0>(stream, {RP[3],srcs_all,w_all, B2,us_i[3],us_w[3],
                                 B0,B1,B3, ccW[0],ccB[0],nullptr, 2,8,64,1});
  run_level<16,16,16,0>(stream, {RP[2],srcs_all,w_all, B3,us_i[2],us_w[2],
                                 B0,B1,B2, ccW[1],ccB[1],nullptr, 2,10,256,1});
  run_level<16,16,16,0>(stream, {RP[1],srcs_all,w_all, B2,us_i[1],us_w[1],
                                 B0,B1,B3, ccW[2],ccB[2],nullptr, 2,12,1024,1});
  run_level<16,16,3,0>(stream, {RP[4],srcs_all,w_all, B3,us_i[0],us_w[0],
                                B0,B1,out_savg, ccW[3],nullptr,nullptr, 2,14,4096,0});

  // ---- decoder s (G=32) ----
  k_zin<<<cdiv(32*64,TPB),TPB,0,stream>>>(muc, mus, zin);
  k_lin<<<cdiv((long long)32*2048,TPB),TPB,0,stream>>>(zin, linsW, linsB, B2, 32, 64, 1);
  run_level<32,32,16,0>(stream, {RP[3],srcs_all,w_all, B2,us_i[3],us_w[3],
                                 B0,B1,B3, csW[0],csB[0],nullptr, 32,8,64,1});
  run_level<16,16,16,0>(stream, {RP[2],srcs_all,w_all, B3,us_i[2],us_w[2],
                                 B0,B1,B2, csW[1],csB[1],nullptr, 32,10,256,1});
  run_level<16,16,16,0>(stream, {RP[1],srcs_all,w_all, B2,us_i[1],us_w[1],
                                 B0,B1,B3, csW[2],csB[2],nullptr, 32,12,1024,1});
  run_level<16,16,3,0>(stream, {RP[4],srcs_all,w_all, B3,us_i[0],us_w[0],
                                B0,B1,out_st, csW[3],nullptr,out_savg, 32,14,4096,0});

  (void)in_sizes; (void)n_in; (void)out_size; (void)ws_size;
}

// Round 12
// 1103.451 us; speedup vs baseline: 2.3721x; 1.2015x over previous
//
#include <hip/hip_runtime.h>
#include <cstdint>
#include <cstddef>

#define TPB 256

typedef float f32x4 __attribute__((ext_vector_type(4)));
typedef float f32x2 __attribute__((ext_vector_type(2)));
typedef int   i32x4 __attribute__((ext_vector_type(4)));

static inline int cdiv(long long a, int b){ return (int)((a + (long long)b - 1) / b); }

// ---- concat level tables: N={16384,4096,1024,256,16384}, E={196608,49152,12288,3072,196608}
#define NTOT 38144
#define ETOT 457728
#define CTOT 762880
#define RPTOT 38149

// ---------------- small vector helpers ----------------

template<int W>
__device__ __forceinline__ void vload(const float* __restrict__ p, float* r){
  if constexpr (W == 8){ vload<4>(p, r); vload<4>(p+4, r+4); }
  else if constexpr (W == 4){ f32x4 v = *reinterpret_cast<const f32x4*>(p); r[0]=v.x;r[1]=v.y;r[2]=v.z;r[3]=v.w; }
  else { f32x2 v = *reinterpret_cast<const f32x2*>(p); r[0]=v.x;r[1]=v.y; }
}
template<int W>
__device__ __forceinline__ void vstore(float* __restrict__ p, const float* r){
  if constexpr (W == 8){ vstore<4>(p, r); vstore<4>(p+4, r+4); }
  else if constexpr (W == 4){ f32x4 v; v.x=r[0];v.y=r[1];v.z=r[2];v.w=r[3]; *reinterpret_cast<f32x4*>(p) = v; }
  else { f32x2 v; v.x=r[0];v.y=r[1]; *reinterpret_cast<f32x2*>(p) = v; }
}

template<int F>
__device__ __forceinline__ void loadrow(const float* __restrict__ p, float* r){
  #pragma unroll
  for (int q = 0; q < F/4; ++q) vload<4>(p + 4*q, r + 4*q);
}
template<int F>
__device__ __forceinline__ void storerow(float* __restrict__ p, const float* r){
  #pragma unroll
  for (int q = 0; q < F/4; ++q) vstore<4>(p + 4*q, r + 4*q);
}

// ---------------- CSR build (fused across 5 levels, rows padded to x8) ----------------

__device__ __forceinline__ bool lvl_edge(int t, const int* e0,const int* e1,const int* e2,const int* e3,const int* e4,
                                         const int*& ei, int& E, int& noff, int& rpoff, int& rel){
  if (t < 196608){ ei=e0; E=196608; noff=0;     rpoff=0;     rel=t;        return true; }
  if (t < 245760){ ei=e1; E=49152;  noff=16384; rpoff=16385; rel=t-196608; return true; }
  if (t < 258048){ ei=e2; E=12288;  noff=20480; rpoff=20482; rel=t-245760; return true; }
  if (t < 261120){ ei=e3; E=3072;   noff=21504; rpoff=21507; rel=t-258048; return true; }
  if (t < 457728){ ei=e4; E=196608; noff=21760; rpoff=21764; rel=t-261120; return true; }
  return false;
}

__global__ void k_degs_all(const int* e0,const int* e1,const int* e2,const int* e3,const int* e4,
                           int* __restrict__ rowdeg, int* __restrict__ dstdeg){
  int t = blockIdx.x*blockDim.x + threadIdx.x;
  const int* ei; int E, noff, rpoff, rel;
  if (!lvl_edge(t, e0,e1,e2,e3,e4, ei,E,noff,rpoff,rel)) return;
  atomicAdd(&rowdeg[noff + ei[rel]], 1);
  atomicAdd(&dstdeg[noff + ei[E + rel]], 1);
}

__global__ void k_dis_all(const int* __restrict__ rowdeg, float* __restrict__ dis){
  int t = blockIdx.x*blockDim.x + threadIdx.x;
  if (t >= NTOT) return;
  int d = rowdeg[t];
  dis[t] = d > 0 ? rsqrtf((float)d) : 0.f;
}

__global__ void k_scan5(const int* __restrict__ dstdeg, int* __restrict__ rp, int* __restrict__ cursor){
  const int NnA[5]  = {16384,4096,1024,256,16384};
  const int NOFF[5] = {0,16384,20480,21504,21760};
  const int COFF[5] = {0,327680,409600,430080,435200};
  __shared__ int part[257];
  int l = blockIdx.x;
  int N = NnA[l];
  const int* cnt = dstdeg + NOFF[l];
  int* rpl = rp + NOFF[l] + l;
  int* cul = cursor + NOFF[l] + l;
  int tid = threadIdx.x;
  int chunk = (N + 255) / 256;
  int lo = tid*chunk; if (lo > N) lo = N;
  int hi = lo + chunk; if (hi > N) hi = N;
  int s = 0;
  for (int i = lo; i < hi; ++i) s += (cnt[i] + 7) & ~7;
  part[tid+1] = s;
  if (tid == 0) part[0] = COFF[l];
  __syncthreads();
  if (tid == 0){ for (int i = 1; i <= 256; ++i) part[i] += part[i-1]; }
  __syncthreads();
  int run = part[tid];
  for (int i = lo; i < hi; ++i){ rpl[i] = run; cul[i] = run; run += (cnt[i] + 7) & ~7; }
  if (tid == 0) rpl[N] = part[256];
}

__global__ void k_fill_all(const int* e0,const int* e1,const int* e2,const int* e3,const int* e4,
                           const float* __restrict__ dis, int* __restrict__ cursor,
                           int* __restrict__ srcs, float* __restrict__ w){
  int t = blockIdx.x*blockDim.x + threadIdx.x;
  const int* ei; int E, noff, rpoff, rel;
  if (!lvl_edge(t, e0,e1,e2,e3,e4, ei,E,noff,rpoff,rel)) return;
  int src = ei[rel], dst = ei[E + rel];
  int pos = atomicAdd(&cursor[rpoff + dst], 1);
  srcs[pos] = src;
  w[pos] = dis[noff + src] * dis[noff + dst];
}

__global__ void k_pad_all(const int* __restrict__ dstdeg, const int* __restrict__ rp,
                          int* __restrict__ srcs, float* __restrict__ w){
  int t = blockIdx.x*blockDim.x + threadIdx.x;
  if (t >= NTOT) return;
  int rpoff, n;
  if      (t < 16384){ rpoff = 0;     n = t; }
  else if (t < 20480){ rpoff = 16385; n = t - 16384; }
  else if (t < 21504){ rpoff = 20482; n = t - 20480; }
  else if (t < 21760){ rpoff = 21507; n = t - 21504; }
  else               { rpoff = 21764; n = t - 21760; }
  int j0 = rp[rpoff + n];
  int j1 = rp[rpoff + n + 1];
  int cnt = dstdeg[t];
  int sfill = cnt > 0 ? srcs[j0] : 0;
  for (int j = j0 + cnt; j < j1; ++j){ srcs[j] = sfill; w[j] = 0.f; }
}

// ================= TRANSPOSED (g-blocked) PATH — G=32 levels =================
// Layout: X_t[gb][n][gs][F], gb<8 (XCD), gs<4, g=(gb<<2)|gs. Row stride 4*F.
// Lane unit: n-unit = F lanes (4gs x LPR), LPR = F/4. 16-lane-ish groups read
// 256B-contiguous neighbor segments -> 4x fewer scattered segments per gather.

template<int FinPad>
__device__ __forceinline__ void tmap(int N, int& gb, int& n, int& gs, int& sub, int& laneoff){
  constexpr int LPR = FinPad/4;
  gb = blockIdx.x & 7;
  int I = (blockIdx.x >> 3)*256 + threadIdx.x;
  n = I / FinPad;
  int u = I - n*FinPad;
  gs = u / LPR;
  sub = u - gs*LPR;
  laneoff = gs*FinPad + sub*4;
}

template<int FinPad>
__device__ __forceinline__ void gather8_t(const float* __restrict__ base,
                                          const int* __restrict__ srcs, const float* __restrict__ w,
                                          int j0, int j1, int laneoff, float* acc){
  constexpr int RS = 4*FinPad;
  #pragma unroll
  for (int q = 0; q < 4; ++q) acc[q] = 0.f;
  for (int j = j0; j < j1; j += 8){
    i32x4 sa = *reinterpret_cast<const i32x4*>(srcs + j);
    i32x4 sb = *reinterpret_cast<const i32x4*>(srcs + j + 4);
    f32x4 wa = *reinterpret_cast<const f32x4*>(w + j);
    f32x4 wb = *reinterpret_cast<const f32x4*>(w + j + 4);
    float v0[4], v1[4], v2[4], v3[4], v4[4], v5[4], v6[4], v7[4];
    vload<4>(base + (size_t)sa.x*RS + laneoff, v0);
    vload<4>(base + (size_t)sa.y*RS + laneoff, v1);
    vload<4>(base + (size_t)sa.z*RS + laneoff, v2);
    vload<4>(base + (size_t)sa.w*RS + laneoff, v3);
    vload<4>(base + (size_t)sb.x*RS + laneoff, v4);
    vload<4>(base + (size_t)sb.y*RS + laneoff, v5);
    vload<4>(base + (size_t)sb.z*RS + laneoff, v6);
    vload<4>(base + (size_t)sb.w*RS + laneoff, v7);
    #pragma unroll
    for (int q = 0; q < 4; ++q){
      acc[q] = fmaf(wa.x, v0[q], acc[q]);
      acc[q] = fmaf(wa.y, v1[q], acc[q]);
      acc[q] = fmaf(wa.z, v2[q], acc[q]);
      acc[q] = fmaf(wa.w, v3[q], acc[q]);
      acc[q] = fmaf(wb.x, v4[q], acc[q]);
      acc[q] = fmaf(wb.y, v5[q], acc[q]);
      acc[q] = fmaf(wb.z, v6[q], acc[q]);
      acc[q] = fmaf(wb.w, v7[q], acc[q]);
    }
  }
}

// ts = lane's 4 floats (f = sub*4..sub*4+3) of the (n,g) row; collect LPR lanes.
template<int FinPad, int FinReal, int Fout>
__device__ __forceinline__ void gemm_t(const float* ts, const float* __restrict__ Wk,
                                       int sub, float* o){
  constexpr int LPR = FinPad/4;
  int lane = (int)threadIdx.x & 63;
  int lanebase = lane & ~(LPR-1);
  float tv[FinPad];
  #pragma unroll
  for (int s = 0; s < LPR; ++s)
    #pragma unroll
    for (int q = 0; q < 4; ++q)
      tv[s*4+q] = __shfl(ts[q], lanebase + s, 64);
  if constexpr (Fout % 4 == 0){
    constexpr int OPL = Fout/LPR;
    #pragma unroll
    for (int fi = 0; fi < FinReal; ++fi)
      #pragma unroll
      for (int q = 0; q < OPL; ++q)
        o[q] = fmaf(tv[fi], Wk[fi*Fout + sub*OPL + q], o[q]);
  } else {
    if (sub < Fout){
      #pragma unroll
      for (int fi = 0; fi < FinReal; ++fi)
        o[0] = fmaf(tv[fi], Wk[fi*Fout + sub], o[0]);
    }
  }
}

// PRE: 1 = phase-encode (enc l0, FinPad==8), 0 = pool from FinPad-layout source
template<int FinPad, int PRE>
__global__ void k_pre_t(const float* __restrict__ psrc, const int* __restrict__ pidx,
                        const float* __restrict__ pw, float* __restrict__ bufX,
                        int N, int Nin){
  int gb, n, gs, sub, laneoff;
  tmap<FinPad>(N, gb, n, gs, sub, laneoff);
  constexpr int RS = 4*FinPad;
  float r[4];
  if constexpr (PRE == 1){
    int g = (gb<<2) | gs;
    int t = g & 15;
    float th = 6.283185307179586f * (float)t / 16.0f;
    float sn, cs; sincosf(th, &sn, &cs);
    const float* xr = psrc + ((size_t)g*16384 + n)*3;
    #pragma unroll
    for (int q = 0; q < 4; ++q){
      int f = sub*4 + q;
      float v = 0.f;
      if (f < 6) v = xr[f % 3] * (f < 3 ? cs : sn);
      r[q] = v;
    }
  } else {
    int i0 = pidx[n*3+0], i1 = pidx[n*3+1], i2 = pidx[n*3+2];
    float w0 = pw[n*3+0], w1 = pw[n*3+1], w2 = pw[n*3+2];
    const float* pb = psrc + (size_t)gb*Nin*RS + laneoff;
    float a[4], b[4], c[4];
    vload<4>(pb + (size_t)i0*RS, a);
    vload<4>(pb + (size_t)i1*RS, b);
    vload<4>(pb + (size_t)i2*RS, c);
    #pragma unroll
    for (int q = 0; q < 4; ++q) r[q] = fmaf(w0, a[q], fmaf(w1, b[q], w2*c[q]));
  }
  vstore<4>(bufX + (size_t)gb*N*RS + (size_t)n*RS + laneoff, r);
}

template<int FinPad, int FinReal, int Fout>
__global__ void k_first_t(const int* __restrict__ rp, const int* __restrict__ srcs, const float* __restrict__ w,
                          const float* __restrict__ bufX, float* __restrict__ bufT1, float* __restrict__ out,
                          const float* __restrict__ W6, const float* __restrict__ bias, int N){
  constexpr int LPR = FinPad/4;
  constexpr int OPL = (Fout % 4 == 0) ? Fout/LPR : 1;
  constexpr int RS = 4*FinPad;
  int gb, n, gs, sub, laneoff;
  tmap<FinPad>(N, gb, n, gs, sub, laneoff);
  const float* gbase = bufX + (size_t)gb*N*RS;
  float t0[4]; vload<4>(gbase + (size_t)n*RS + laneoff, t0);
  float t1[4];
  gather8_t<FinPad>(gbase, srcs, w, rp[n], rp[n+1], laneoff, t1);
  vstore<4>(bufT1 + (size_t)gb*N*RS + (size_t)n*RS + laneoff, t1);
  float o[OPL];
  if constexpr (Fout % 4 == 0){
    #pragma unroll
    for (int q = 0; q < OPL; ++q) o[q] = bias ? bias[sub*OPL + q] : 0.f;
  } else {
    o[0] = (bias && sub < Fout) ? bias[sub] : 0.f;
  }
  gemm_t<FinPad,FinReal,Fout>(t0, W6, sub, o);
  gemm_t<FinPad,FinReal,Fout>(t1, W6 + (size_t)FinReal*Fout, sub, o);
  if constexpr (Fout % 4 == 0){
    vstore<OPL>(out + ((size_t)(gb*N + n)*4 + gs)*Fout + sub*OPL, o);
  } else {
    if (sub < Fout){
      int g = (gb<<2)|gs;
      out[((size_t)g*N + n)*3 + sub] = o[0];
    }
  }
}

template<int FinPad, int FinReal, int Fout>
__global__ void k_step_t(const int* __restrict__ rp, const int* __restrict__ srcs, const float* __restrict__ w,
                         const float* __restrict__ Tm1, float* __restrict__ P, float* __restrict__ out,
                         const float* __restrict__ Wk, const float* __restrict__ savg,
                         int N, int relu, int last){
  constexpr int LPR = FinPad/4;
  constexpr int OPL = (Fout % 4 == 0) ? Fout/LPR : 1;
  constexpr int RS = 4*FinPad;
  int gb, n, gs, sub, laneoff;
  tmap<FinPad>(N, gb, n, gs, sub, laneoff);
  const float* gbase = Tm1 + (size_t)gb*N*RS;
  float tk[4];
  gather8_t<FinPad>(gbase, srcs, w, rp[n], rp[n+1], laneoff, tk);
  float tm2[4]; vload<4>(P + (size_t)gb*N*RS + (size_t)n*RS + laneoff, tm2);
  #pragma unroll
  for (int q = 0; q < 4; ++q) tk[q] = 2.f*tk[q] - tm2[q];
  if (!last) vstore<4>(P + (size_t)gb*N*RS + (size_t)n*RS + laneoff, tk);
  float o[OPL];
  if constexpr (Fout % 4 == 0){
    vload<OPL>(out + ((size_t)(gb*N + n)*4 + gs)*Fout + sub*OPL, o);
  } else {
    o[0] = 0.f;
    if (sub < Fout) o[0] = out[((size_t)((gb<<2)|gs)*N + n)*3 + sub];
  }
  gemm_t<FinPad,FinReal,Fout>(tk, Wk, sub, o);
  if constexpr (Fout % 4 == 0){
    if (last && relu){
      #pragma unroll
      for (int q = 0; q < OPL; ++q) o[q] = fmaxf(o[q], 0.f);
    }
    vstore<OPL>(out + ((size_t)(gb*N + n)*4 + gs)*Fout + sub*OPL, o);
  } else {
    if (sub < Fout){
      float v = o[0];
      if (last && relu) v = fmaxf(v, 0.f);
      int g = (gb<<2)|gs;
      if (last && savg) v += savg[((size_t)(g>>4)*N + n)*3 + sub];
      out[((size_t)g*N + n)*3 + sub] = v;
    }
  }
}

// ================= OLD (row-major) PATH — decoder-c (G=2) =================

template<int FPL, int FinPad>
__device__ __forceinline__ void gather8(const float* __restrict__ gb,
                                        const int* __restrict__ srcs, const float* __restrict__ w,
                                        int j0, int j1, int sub, float* acc){
  #pragma unroll
  for (int q = 0; q < FPL; ++q) acc[q] = 0.f;
  for (int j = j0; j < j1; j += 8){
    i32x4 sa = *reinterpret_cast<const i32x4*>(srcs + j);
    i32x4 sb = *reinterpret_cast<const i32x4*>(srcs + j + 4);
    f32x4 wa = *reinterpret_cast<const f32x4*>(w + j);
    f32x4 wb = *reinterpret_cast<const f32x4*>(w + j + 4);
    float v0[FPL], v1[FPL], v2[FPL], v3[FPL], v4[FPL], v5[FPL], v6[FPL], v7[FPL];
    vload<FPL>(gb + (size_t)sa.x*FinPad + sub*FPL, v0);
    vload<FPL>(gb + (size_t)sa.y*FinPad + sub*FPL, v1);
    vload<FPL>(gb + (size_t)sa.z*FinPad + sub*FPL, v2);
    vload<FPL>(gb + (size_t)sa.w*FinPad + sub*FPL, v3);
    vload<FPL>(gb + (size_t)sb.x*FinPad + sub*FPL, v4);
    vload<FPL>(gb + (size_t)sb.y*FinPad + sub*FPL, v5);
    vload<FPL>(gb + (size_t)sb.z*FinPad + sub*FPL, v6);
    vload<FPL>(gb + (size_t)sb.w*FinPad + sub*FPL, v7);
    #pragma unroll
    for (int q = 0; q < FPL; ++q){
      acc[q] = fmaf(wa.x, v0[q], acc[q]);
      acc[q] = fmaf(wa.y, v1[q], acc[q]);
      acc[q] = fmaf(wa.z, v2[q], acc[q]);
      acc[q] = fmaf(wa.w, v3[q], acc[q]);
      acc[q] = fmaf(wb.x, v4[q], acc[q]);
      acc[q] = fmaf(wb.y, v5[q], acc[q]);
      acc[q] = fmaf(wb.z, v6[q], acc[q]);
      acc[q] = fmaf(wb.w, v7[q], acc[q]);
    }
  }
}

template<int FinPad, int FinReal, int Fout>
__device__ __forceinline__ void gemm_acc(const float* ts, const float* __restrict__ Wk,
                                         int sub, int lanebase, float* o){
  constexpr int FPL = FinPad/4;
  float tv[FinPad];
  #pragma unroll
  for (int s = 0; s < 4; ++s)
    #pragma unroll
    for (int q = 0; q < FPL; ++q)
      tv[s*FPL+q] = __shfl(ts[q], lanebase + s, 64);
  if constexpr (Fout % 4 == 0){
    constexpr int OPL = Fout/4;
    #pragma unroll
    for (int fi = 0; fi < FinReal; ++fi)
      #pragma unroll
      for (int q = 0; q < OPL; ++q)
        o[q] = fmaf(tv[fi], Wk[fi*Fout + sub*OPL + q], o[q]);
  } else {
    if (sub < Fout){
      #pragma unroll
      for (int fi = 0; fi < FinReal; ++fi)
        o[0] = fmaf(tv[fi], Wk[fi*Fout + sub], o[0]);
    }
  }
}

template<int FinPad>
__device__ __forceinline__ void pool_row(const float* __restrict__ psrc, const int* __restrict__ pidx,
                                         const float* __restrict__ pw, int n, int g, int Nin, int sub,
                                         float* r){
  constexpr int FPL = FinPad/4;
  int i0 = pidx[n*3+0], i1 = pidx[n*3+1], i2 = pidx[n*3+2];
  float w0 = pw[n*3+0], w1 = pw[n*3+1], w2 = pw[n*3+2];
  const float* bsrc = psrc + (size_t)g*Nin*FinPad + sub*FPL;
  float a[FPL], b[FPL], c[FPL];
  vload<FPL>(bsrc + (size_t)i0*FinPad, a);
  vload<FPL>(bsrc + (size_t)i1*FinPad, b);
  vload<FPL>(bsrc + (size_t)i2*FinPad, c);
  #pragma unroll
  for (int q = 0; q < FPL; ++q) r[q] = fmaf(w0, a[q], fmaf(w1, b[q], w2*c[q]));
}

template<int FinPad>
__global__ void k_pre_f(const float* __restrict__ psrc, const int* __restrict__ pidx,
                        const float* __restrict__ pw, float* __restrict__ bufX,
                        int G, int logN, int Nin){
  constexpr int FPL = FinPad/4;
  long long i4 = (long long)blockIdx.x*blockDim.x + threadIdx.x;
  if (i4 >= ((long long)G << logN)*4) return;
  int sub = (int)(i4 & 3);
  long long i = i4 >> 2;
  int N = 1 << logN;
  int n = (int)(i & (N-1));
  int g = (int)(i >> logN);
  float r[FPL];
  pool_row<FinPad>(psrc, pidx, pw, n, g, Nin, sub, r);
  vstore<FPL>(bufX + (size_t)i*FinPad + sub*FPL, r);
}

template<int FinPad, int FinReal, int Fout>
__global__ void k_first_f(const int* __restrict__ rp, const int* __restrict__ srcs, const float* __restrict__ w,
                          const float* __restrict__ bufX, float* __restrict__ bufT1, float* __restrict__ out,
                          const float* __restrict__ W6, const float* __restrict__ bias,
                          int G, int logN){
  constexpr int FPL = FinPad/4;
  constexpr int OPL = (Fout % 4 == 0) ? Fout/4 : 1;
  long long i4 = (long long)blockIdx.x*blockDim.x + threadIdx.x;
  if (i4 >= ((long long)G << logN)*4) return;
  int sub = (int)(i4 & 3);
  long long i = i4 >> 2;
  int N = 1 << logN;
  int n = (int)(i & (N-1));
  int lanebase = ((int)threadIdx.x & 63) & ~3;
  const float* gb = bufX + (size_t)(i - n)*FinPad;
  float t0[FPL]; vload<FPL>(bufX + (size_t)i*FinPad + sub*FPL, t0);
  float t1[FPL];
  gather8<FPL,FinPad>(gb, srcs, w, rp[n], rp[n+1], sub, t1);
  vstore<FPL>(bufT1 + (size_t)i*FinPad + sub*FPL, t1);
  float o[OPL];
  if constexpr (Fout % 4 == 0){
    #pragma unroll
    for (int q = 0; q < OPL; ++q) o[q] = bias ? bias[sub*OPL + q] : 0.f;
  } else {
    o[0] = (bias && sub < Fout) ? bias[sub] : 0.f;
  }
  gemm_acc<FinPad,FinReal,Fout>(t0, W6, sub, lanebase, o);
  gemm_acc<FinPad,FinReal,Fout>(t1, W6 + (size_t)FinReal*Fout, sub, lanebase, o);
  if constexpr (Fout % 4 == 0) vstore<OPL>(out + (size_t)i*Fout + sub*OPL, o);
  else if (sub < Fout) out[(size_t)i*Fout + sub] = o[0];
}

template<int FinPad, int FinReal, int Fout>
__global__ void k_step_f(const int* __restrict__ rp, const int* __restrict__ srcs, const float* __restrict__ w,
                         const float* __restrict__ Tm1, float* __restrict__ P, float* __restrict__ out,
                         const float* __restrict__ Wk, const float* __restrict__ savg,
                         int G, int logN, int relu, int last){
  constexpr int FPL = FinPad/4;
  constexpr int OPL = (Fout % 4 == 0) ? Fout/4 : 1;
  long long i4 = (long long)blockIdx.x*blockDim.x + threadIdx.x;
  if (i4 >= ((long long)G << logN)*4) return;
  int sub = (int)(i4 & 3);
  long long i = i4 >> 2;
  int N = 1 << logN;
  int n = (int)(i & (N-1));
  int lanebase = ((int)threadIdx.x & 63) & ~3;
  const float* gb = Tm1 + (size_t)(i - n)*FinPad;
  float tk[FPL];
  gather8<FPL,FinPad>(gb, srcs, w, rp[n], rp[n+1], sub, tk);
  float tm2[FPL]; vload<FPL>(P + (size_t)i*FinPad + sub*FPL, tm2);
  #pragma unroll
  for (int q = 0; q < FPL; ++q) tk[q] = 2.f*tk[q] - tm2[q];
  if (!last) vstore<FPL>(P + (size_t)i*FinPad + sub*FPL, tk);
  float o[OPL];
  if constexpr (Fout % 4 == 0) vload<OPL>(out + (size_t)i*Fout + sub*OPL, o);
  else { o[0] = (sub < Fout) ? out[(size_t)i*Fout + sub] : 0.f; }
  gemm_acc<FinPad,FinReal,Fout>(tk, Wk, sub, lanebase, o);
  if constexpr (Fout % 4 == 0){
    if (last && relu){
      #pragma unroll
      for (int q = 0; q < OPL; ++q) o[q] = fmaxf(o[q], 0.f);
    }
    vstore<OPL>(out + (size_t)i*Fout + sub*OPL, o);
  } else {
    if (sub < Fout){
      float v = o[0];
      if (last && relu) v = fmaxf(v, 0.f);
      if (last && savg){
        int g = (int)(i >> logN);
        v += savg[((size_t)(g>>4)*N + n)*3 + sub];
      }
      out[(size_t)i*Fout + sub] = v;
    }
  }
}

// ---------------- latent / misc kernels ----------------

// hmu_t layout: [gb][n<64][gs][32]; element (g, f2=n*32+f)
__global__ void k_mu_t(const float* __restrict__ h_t, const float* __restrict__ W,
                       const float* __restrict__ b, float* __restrict__ mu){
  int wid = (blockIdx.x*blockDim.x + threadIdx.x) >> 6;
  int lane = threadIdx.x & 63;
  if (wid >= 32*48) return;
  int z = wid % 48, g = wid / 48;
  const float* wr = W + (size_t)z*2048;
  const float* hb = h_t + (size_t)(g>>2)*64*128 + (g&3)*32;
  float acc = 0.f;
  for (int f2 = lane; f2 < 2048; f2 += 64)
    acc = fmaf(hb[(size_t)(f2>>5)*128 + (f2&31)], wr[f2], acc);
  for (int o = 32; o > 0; o >>= 1) acc += __shfl_down(acc, o, 64);
  if (lane == 0) mu[wid] = acc + b[z];
}

__global__ void k_mucs(const float* __restrict__ mu, float* __restrict__ muc,
                       float* __restrict__ mus, float* __restrict__ out){
  int i = blockIdx.x*blockDim.x + threadIdx.x;
  if (i >= 96) return;
  int z = i % 48, bp = i / 48;
  float acc = 0.f;
  for (int b = 0; b < 2; ++b)
    for (int t = 8*bp; t < 8*bp + 8; ++t)
      acc += mu[(b*16 + t)*48 + z];
  acc *= (1.f/16.f);
  if (z < 32){ muc[bp*32 + z] = acc; out[bp*32 + z] = acc; }
  else       { mus[bp*16 + (z-32)] = acc; out[64 + bp*16 + (z-32)] = acc; }
}

__global__ void k_zin(const float* __restrict__ muc, const float* __restrict__ mus,
                      float* __restrict__ zin){
  int i = blockIdx.x*blockDim.x + threadIdx.x;
  if (i >= 32*64) return;
  int c = i % 64, g = i / 64;
  int b = g / 16, t = g % 16;
  float v;
  if (c < 32){
    v = muc[b*32 + c];
  } else {
    float th = 6.283185307179586f * (float)t / 16.0f;
    int k = c - 32;
    int kk = (k < 16) ? k : (k - 16);
    float m = mus[b*16 + kk];
    v = (k < 16) ? m * cosf(th) : m * sinf(th);
  }
  zin[i] = v;
}

// plain (row-major output) linear — decoder-c
__global__ void k_lin(const float* __restrict__ z, const float* __restrict__ W,
                      const float* __restrict__ b, float* __restrict__ y,
                      int G, int Z, int relu){
  int i = blockIdx.x*blockDim.x + threadIdx.x;
  if (i >= G*2048) return;
  int f = i % 2048, g = i / 2048;
  const float* zr = z + (size_t)g*Z;
  const float* wr = W + (size_t)f*Z;
  float acc = b[f];
  for (int k = 0; k < Z; ++k) acc = fmaf(zr[k], wr[k], acc);
  if (relu) acc = fmaxf(acc, 0.f);
  y[i] = acc;
}

// transposed-write linear — decoder-s (y_t[gb][n<64][gs][32])
__global__ void k_lin_t(const float* __restrict__ z, const float* __restrict__ W,
                        const float* __restrict__ b, float* __restrict__ y_t,
                        int Z, int relu){
  int i = blockIdx.x*blockDim.x + threadIdx.x;
  if (i >= 32*2048) return;
  int f2 = i % 2048, g = i / 2048;
  const float* zr = z + (size_t)g*Z;
  const float* wr = W + (size_t)f2*Z;
  float acc = b[f2];
  for (int k = 0; k < Z; ++k) acc = fmaf(zr[k], wr[k], acc);
  if (relu) acc = fmaxf(acc, 0.f);
  y_t[(size_t)(g>>2)*64*128 + (size_t)(f2>>5)*128 + (g&3)*32 + (f2&31)] = acc;
}

// ---------------- host orchestration ----------------

struct LvlArgs {
  const int* rp; const int* srcs; const float* w;
  const float* psrc; const int* pidx; const float* pw;
  float* bufX; float* bufT1; float* out;
  const float* W6; const float* bias; const float* savg;
  int G; int logN; int Nin; int relu;
};

// transposed level (G=32)
template<int FinPad, int FinReal, int Fout, int PRE>
static void run_level_t(hipStream_t s, const LvlArgs& a){
  int N = 1 << a.logN;
  int grid = 8 * (N*FinPad/256);
  k_pre_t<FinPad,PRE><<<grid,256,0,s>>>(a.psrc, a.pidx, a.pw, a.bufX, N, a.Nin);
  k_first_t<FinPad,FinReal,Fout><<<grid,256,0,s>>>(a.rp, a.srcs, a.w, a.bufX, a.bufT1, a.out,
                                                   a.W6, a.bias, N);
  float* Ab = a.bufT1; float* Bb = a.bufX;
  for (int k = 2; k <= 5; ++k){
    int last = (k == 5) ? 1 : 0;
    k_step_t<FinPad,FinReal,Fout><<<grid,256,0,s>>>(a.rp, a.srcs, a.w, Ab, Bb, a.out,
                                                    a.W6 + (size_t)k*FinReal*Fout,
                                                    last ? a.savg : nullptr,
                                                    N, a.relu, last);
    float* t = Ab; Ab = Bb; Bb = t;
  }
}

// old-layout level (decoder-c, G=2)
template<int FinPad, int FinReal, int Fout>
static void run_level_f(hipStream_t s, const LvlArgs& a){
  long long GN4 = ((long long)a.G << a.logN) * 4;
  int grid = cdiv(GN4, 256);
  k_pre_f<FinPad><<<grid,256,0,s>>>(a.psrc, a.pidx, a.pw, a.bufX, a.G, a.logN, a.Nin);
  k_first_f<FinPad,FinReal,Fout><<<grid,256,0,s>>>(a.rp, a.srcs, a.w, a.bufX, a.bufT1, a.out,
                                                   a.W6, a.bias, a.G, a.logN);
  float* Ab = a.bufT1; float* Bb = a.bufX;
  for (int k = 2; k <= 5; ++k){
    int last = (k == 5) ? 1 : 0;
    k_step_f<FinPad,FinReal,Fout><<<grid,256,0,s>>>(a.rp, a.srcs, a.w, Ab, Bb, a.out,
                                                    a.W6 + (size_t)k*FinReal*Fout,
                                                    last ? a.savg : nullptr,
                                                    a.G, a.logN, a.relu, last);
    float* t = Ab; Ab = Bb; Bb = t;
  }
}

extern "C" void kernel_launch(void* const* d_in, const int* in_sizes, int n_in,
                              void* d_out, int out_size, void* d_ws, size_t ws_size,
                              hipStream_t stream){
  const float* x = (const float*)d_in[0];
  const float* encW[4] = {(const float*)d_in[1],(const float*)d_in[3],(const float*)d_in[5],(const float*)d_in[7]};
  const float* encB[4] = {(const float*)d_in[2],(const float*)d_in[4],(const float*)d_in[6],(const float*)d_in[8]};
  const float* ccW[4]  = {(const float*)d_in[9],(const float*)d_in[11],(const float*)d_in[13],(const float*)d_in[15]};
  const float* ccB[3]  = {(const float*)d_in[10],(const float*)d_in[12],(const float*)d_in[14]};
  const float* csW[4]  = {(const float*)d_in[16],(const float*)d_in[18],(const float*)d_in[20],(const float*)d_in[22]};
  const float* csB[3]  = {(const float*)d_in[17],(const float*)d_in[19],(const float*)d_in[21]};
  const float* muW  = (const float*)d_in[23]; const float* muB  = (const float*)d_in[24];
  const float* lincW = (const float*)d_in[25]; const float* lincB = (const float*)d_in[26];
  const float* linsW = (const float*)d_in[27]; const float* linsB = (const float*)d_in[28];
  const int* ei[5] = {(const int*)d_in[29],(const int*)d_in[30],(const int*)d_in[31],
                      (const int*)d_in[32],(const int*)d_in[33]};
  const int* ds_i[4]; const float* ds_w[4]; const int* us_i[4]; const float* us_w[4];
  for (int l = 0; l < 4; ++l){
    ds_i[l] = (const int*)d_in[34 + 4*l]; ds_w[l] = (const float*)d_in[35 + 4*l];
    us_i[l] = (const int*)d_in[36 + 4*l]; us_w[l] = (const float*)d_in[37 + 4*l];
  }

  float* ws = (float*)d_ws;
  const size_t BIG = 8388608;
  float* B0 = ws + 0*BIG;
  float* B1 = ws + 1*BIG;
  float* B2 = ws + 2*BIG;
  float* B3 = ws + 3*BIG;
  size_t off = 4*BIG;

  int*   rp_all     = (int*)(ws + off); off += RPTOT;
  int*   cursor_all = (int*)(ws + off); off += RPTOT;
  off = (off + 3) & ~(size_t)3;
  int*   srcs_all   = (int*)(ws + off); off += CTOT;
  float* w_all      =        ws + off;  off += CTOT;
  int*   rowdeg     = (int*)(ws + off); off += NTOT;
  int*   dstdeg     = (int*)(ws + off); off += NTOT;
  float* dis        =        ws + off;  off += NTOT;
  float* hmu        =        ws + off;  off += (size_t)32*2048;
  float* mu         =        ws + off;  off += (size_t)32*48;
  float* muc        =        ws + off;  off += 64;
  float* mus        =        ws + off;  off += 32;
  float* zin        =        ws + off;  off += (size_t)32*64;

  float* outp = (float*)d_out;
  float* out_savg = outp + 96;
  float* out_st   = outp + 96 + 98304;

  // ---- CSR build (6 dispatches) ----
  hipMemsetAsync(rowdeg, 0, 2*(size_t)NTOT*sizeof(int), stream);
  k_degs_all<<<cdiv(ETOT,TPB),TPB,0,stream>>>(ei[0],ei[1],ei[2],ei[3],ei[4], rowdeg, dstdeg);
  k_dis_all<<<cdiv(NTOT,TPB),TPB,0,stream>>>(rowdeg, dis);
  k_scan5<<<5,256,0,stream>>>(dstdeg, rp_all, cursor_all);
  k_fill_all<<<cdiv(ETOT,TPB),TPB,0,stream>>>(ei[0],ei[1],ei[2],ei[3],ei[4], dis, cursor_all, srcs_all, w_all);
  k_pad_all<<<cdiv(NTOT,TPB),TPB,0,stream>>>(dstdeg, rp_all, srcs_all, w_all);

  const int RPOFF[5] = {0,16385,20482,21507,21764};
  const int* RP[5];
  for (int l = 0; l < 5; ++l) RP[l] = rp_all + RPOFF[l];

  // ---- encoder (transposed path, G=32) ----
  run_level_t<8,6,16,1>(stream, {RP[0],srcs_all,w_all, x,nullptr,nullptr,
                                 B0,B1,B2, encW[0],encB[0],nullptr, 32,14,0,1});
  run_level_t<16,16,16,0>(stream, {RP[1],srcs_all,w_all, B2,ds_i[0],ds_w[0],
                                   B0,B1,B3, encW[1],encB[1],nullptr, 32,12,16384,1});
  run_level_t<16,16,16,0>(stream, {RP[2],srcs_all,w_all, B3,ds_i[1],ds_w[1],
                                   B0,B1,B2, encW[2],encB[2],nullptr, 32,10,4096,1});
  run_level_t<16,16,32,0>(stream, {RP[3],srcs_all,w_all, B2,ds_i[2],ds_w[2],
                                   B0,B1,B3, encW[3],encB[3],nullptr, 32,8,1024,1});
  // pool ds3 (256->64, F=32) into hmu_t via transposed pre kernel
  {
    int grid = 8 * (64*32/256);  // 64 nodes * 32 lanes / 256 per gb
    k_pre_t<32,0><<<grid,256,0,stream>>>(B3, ds_i[3], ds_w[3], hmu, 64, 256);
  }

  // ---- latent ----
  k_mu_t<<<cdiv((long long)32*48*64,TPB),TPB,0,stream>>>(hmu, muW, muB, mu);
  k_mucs<<<1,128,0,stream>>>(mu, muc, mus, outp);

  // ---- decoder c (G=2, old path) ----
  k_lin<<<cdiv((long long)2*2048,TPB),TPB,0,stream>>>(muc, lincW, lincB, B2, 2, 32, 0);
  run_level_f<32,32,16>(stream, {RP[3],srcs_all,w_all, B2,us_i[3],us_w[3],
                                 B0,B1,B3, ccW[0],ccB[0],nullptr, 2,8,64,1});
  run_level_f<16,16,16>(stream, {RP[2],srcs_all,w_all, B3,us_i[2],us_w[2],
                                 B0,B1,B2, ccW[1],ccB[1],nullptr, 2,10,256,1});
  run_level_f<16,16,16>(stream, {RP[1],srcs_all,w_all, B2,us_i[1],us_w[1],
                                 B0,B1,B3, ccW[2],ccB[2],nullptr, 2,12,1024,1});
  run_level_f<16,16,3>(stream, {RP[4],srcs_all,w_all, B3,us_i[0],us_w[0],
                                B0,B1,out_savg, ccW[3],nullptr,nullptr, 2,14,4096,0});

  // ---- decoder s (G=32, transposed path) ----
  k_zin<<<cdiv(32*64,TPB),TPB,0,stream>>>(muc, mus, zin);
  k_lin_t<<<cdiv((long long)32*2048,TPB),TPB,0,stream>>>(zin, linsW, linsB, B2, 64, 1);
  run_level_t<32,32,16,0>(stream, {RP[3],srcs_all,w_all, B2,us_i[3],us_w[3],
                                   B0,B1,B3, csW[0],csB[0],nullptr, 32,8,64,1});
  run_level_t<16,16,16,0>(stream, {RP[2],srcs_all,w_all, B3,us_i[2],us_w[2],
                                   B0,B1,B2, csW[1],csB[1],nullptr, 32,10,256,1});
  run_level_t<16,16,16,0>(stream, {RP[1],srcs_all,w_all, B2,us_i[1],us_w[1],
                                   B0,B1,B3, csW[2],csB[2],nullptr, 32,12,1024,1});
  run_level_t<16,16,3,0>(stream, {RP[4],srcs_all,w_all, B3,us_i[0],us_w[0],
                                  B0,B1,out_st, csW[3],nullptr,out_savg, 32,14,4096,0});

  (void)in_sizes; (void)n_in; (void)out_size; (void)ws_size;
}